// Round 1
// baseline (4371.390 us; speedup 1.0000x reference)
//
#include <hip/hip_runtime.h>
#include <math.h>

#define NB 2          // batch
#define LB 32         // blocks
#define BLKN 64       // block size
#define MM 65         // block + router
#define SS (LB*MM)    // 2080
#define DD 512
#define NH 8
#define HD 64
#define FFH 1024
#define ROWS (NB*SS)  // 4160
#define NEGINF -3.402823466e38f

// ---------------- build h: insert router token ----------------
__global__ void build_h_k(const float* __restrict__ x, const float* __restrict__ rt,
                          float* __restrict__ h) {
    int idx = blockIdx.x * blockDim.x + threadIdx.x;   // over NB*SS*DD
    int d = idx % DD;
    int s = (idx / DD) % SS;
    int b = idx / (DD * SS);
    int l = s / MM, j = s % MM;
    float v = (j < BLKN) ? x[((size_t)(b * LB + l) * BLKN + j) * DD + d] : rt[d];
    h[idx] = v;
}

// ---------------- rmsnorm ----------------
__global__ __launch_bounds__(256) void rmsnorm_k(const float* __restrict__ in,
                                                 const float* __restrict__ w,
                                                 float* __restrict__ out) {
    int row = blockIdx.x;
    const float* xr = in + (size_t)row * DD;
    float* orow = out + (size_t)row * DD;
    int t = threadIdx.x;
    float v0 = xr[t], v1 = xr[t + 256];
    float ss = v0 * v0 + v1 * v1;
    #pragma unroll
    for (int off = 32; off; off >>= 1) ss += __shfl_xor(ss, off);
    __shared__ float red[4];
    if ((t & 63) == 0) red[t >> 6] = ss;
    __syncthreads();
    float tot = red[0] + red[1] + red[2] + red[3];
    float r = rsqrtf(tot * (1.0f / 512.0f) + 1e-5f);
    orow[t] = v0 * r * w[t];
    orow[t + 256] = v1 * r * w[t + 256];
}

// ---------------- tiled f32 GEMM: C[ROWS,N] (+)= A[ROWS,K] @ W[K,N] ----------------
template <int ADD>
__global__ __launch_bounds__(256) void gemm64_k(const float* __restrict__ A,
                                                const float* __restrict__ W,
                                                float* __restrict__ C, int K, int N) {
    __shared__ float As[16][68];
    __shared__ float Bs[16][68];
    int t = threadIdx.x;
    int tx = t & 15, ty = t >> 4;
    int rowBase = blockIdx.y * 64, colBase = blockIdx.x * 64;
    float acc[4][4];
    #pragma unroll
    for (int i = 0; i < 4; ++i)
        #pragma unroll
        for (int j = 0; j < 4; ++j) acc[i][j] = 0.0f;

    for (int k0 = 0; k0 < K; k0 += 16) {
        {   // A tile: 64 rows x 16 k
            int r = t >> 2;
            int kk = (t & 3) * 4;
            const float4 a4 = *(const float4*)(A + (size_t)(rowBase + r) * K + k0 + kk);
            As[kk + 0][r] = a4.x; As[kk + 1][r] = a4.y;
            As[kk + 2][r] = a4.z; As[kk + 3][r] = a4.w;
        }
        {   // B tile: 16 k x 64 cols
            int kk = t >> 4;
            int c = (t & 15) * 4;
            *(float4*)(&Bs[kk][c]) = *(const float4*)(W + (size_t)(k0 + kk) * N + colBase + c);
        }
        __syncthreads();
        #pragma unroll
        for (int kk = 0; kk < 16; ++kk) {
            float4 a = *(const float4*)(&As[kk][ty * 4]);
            float4 b = *(const float4*)(&Bs[kk][tx * 4]);
            acc[0][0] += a.x * b.x; acc[0][1] += a.x * b.y; acc[0][2] += a.x * b.z; acc[0][3] += a.x * b.w;
            acc[1][0] += a.y * b.x; acc[1][1] += a.y * b.y; acc[1][2] += a.y * b.z; acc[1][3] += a.y * b.w;
            acc[2][0] += a.z * b.x; acc[2][1] += a.z * b.y; acc[2][2] += a.z * b.z; acc[2][3] += a.z * b.w;
            acc[3][0] += a.w * b.x; acc[3][1] += a.w * b.y; acc[3][2] += a.w * b.z; acc[3][3] += a.w * b.w;
        }
        __syncthreads();
    }
    #pragma unroll
    for (int i = 0; i < 4; ++i) {
        float* crow = C + (size_t)(rowBase + ty * 4 + i) * N + colBase + tx * 4;
        if (ADD) {
            float4 c = *(const float4*)crow;
            c.x += acc[i][0]; c.y += acc[i][1]; c.z += acc[i][2]; c.w += acc[i][3];
            *(float4*)crow = c;
        } else {
            float4 c = make_float4(acc[i][0], acc[i][1], acc[i][2], acc[i][3]);
            *(float4*)crow = c;
        }
    }
}

// ---------------- rotary on q and k (in-place in qkv) ----------------
__global__ void rope_k(float* __restrict__ qkv) {
    int idx = blockIdx.x * blockDim.x + threadIdx.x;  // NB*SS*NH*32
    int j = idx & 31;
    int h = (idx >> 5) & 7;
    int s = (idx >> 8) % SS;
    int b = idx / (256 * SS);
    float inv = powf(1e-4f, (float)j * (1.0f / 32.0f));
    float fr = (float)s * inv;
    float c = cosf(fr), sn = sinf(fr);
    size_t base = ((size_t)(b * SS + s)) * 1536 + h * 64 + j;
    float q1 = qkv[base], q2 = qkv[base + 32];
    qkv[base] = q1 * c + q2 * sn;
    qkv[base + 32] = -q1 * sn + q2 * c;
    float k1 = qkv[base + 512], k2 = qkv[base + 544];
    qkv[base + 512] = k1 * c + k2 * sn;
    qkv[base + 544] = -k1 * sn + k2 * c;
}

// ---------------- attention: one wave per (b,h,q) ----------------
__global__ __launch_bounds__(64) void attn_k(const float* __restrict__ qkv,
                                             const int* __restrict__ doc,
                                             float* __restrict__ o) {
    int q = blockIdx.x % SS;
    int h = (blockIdx.x / SS) % NH;
    int b = blockIdx.x / (SS * NH);
    int lane = threadIdx.x;
    int blkq = q / MM;
    int kmax = (blkq + 1) * MM;

    __shared__ float qs[64];
    __shared__ float sc[SS];

    const float* qrow = qkv + ((size_t)(b * SS + q)) * 1536 + h * 64;
    qs[lane] = qrow[lane];
    __syncthreads();

    int myDoc = doc[b * SS + q];
    const float scale = 0.125f;   // 1/sqrt(64)

    for (int k = lane; k < kmax; k += 64) {
        const float* krow = qkv + ((size_t)(b * SS + k)) * 1536 + 512 + h * 64;
        float dot = 0.0f;
        #pragma unroll
        for (int d2 = 0; d2 < 16; ++d2) {
            float4 kq = *(const float4*)(krow + d2 * 4);
            float4 qq = *(const float4*)(qs + d2 * 4);
            dot += kq.x * qq.x + kq.y * qq.y + kq.z * qq.z + kq.w * qq.w;
        }
        bool ok = (doc[b * SS + k] == myDoc);
        sc[k] = ok ? dot * scale : NEGINF;
    }
    __syncthreads();

    float m = NEGINF;
    for (int k = lane; k < kmax; k += 64) m = fmaxf(m, sc[k]);
    #pragma unroll
    for (int off = 32; off; off >>= 1) m = fmaxf(m, __shfl_xor(m, off));

    float l = 0.0f;
    for (int k = lane; k < kmax; k += 64) {
        float e = expf(sc[k] - m);
        sc[k] = e;
        l += e;
    }
    #pragma unroll
    for (int off = 32; off; off >>= 1) l += __shfl_xor(l, off);
    __syncthreads();

    float inv_l = 1.0f / l;
    float acc = 0.0f;
    for (int k = 0; k < kmax; ++k) {
        const float* vrow = qkv + ((size_t)(b * SS + k)) * 1536 + 1024 + h * 64;
        acc += sc[k] * vrow[lane];
    }
    o[((size_t)(b * SS + q)) * DD + h * 64 + lane] = acc * inv_l;
}

// ---------------- SwiGLU ----------------
__global__ void silu_k(const float* __restrict__ u, float* __restrict__ g) {
    int idx = blockIdx.x * blockDim.x + threadIdx.x;  // ROWS*FFH
    int j = idx % FFH;
    size_t r = idx / FFH;
    float a = u[r * 2048 + j];
    float b = u[r * 2048 + 1024 + j];
    g[idx] = (a / (1.0f + expf(-a))) * b;
}

// ---------------- extract router slots ----------------
__global__ void extract_k(const float* __restrict__ h, float* __restrict__ out) {
    int idx = blockIdx.x * blockDim.x + threadIdx.x;  // NB*LB*DD
    int d = idx % DD;
    int l = (idx / DD) % LB;
    int b = idx / (DD * LB);
    out[idx] = h[((size_t)(b * SS + l * MM + BLKN)) * DD + d];
}

extern "C" void kernel_launch(void* const* d_in, const int* in_sizes, int n_in,
                              void* d_out, int out_size, void* d_ws, size_t ws_size,
                              hipStream_t stream) {
    const float* x           = (const float*)d_in[0];
    const int*   doc         = (const int*)d_in[1];
    const float* rt          = (const float*)d_in[2];
    const float* attn_w      = (const float*)d_in[3];
    const float* attn_o_w    = (const float*)d_in[4];
    const float* ffn_up_w    = (const float*)d_in[5];
    const float* ffn_down_w  = (const float*)d_in[6];
    const float* attn_norm_w = (const float*)d_in[7];
    const float* ffn_norm_w  = (const float*)d_in[8];
    float* out = (float*)d_out;

    float* h   = (float*)d_ws;                       // ROWS*512
    float* hn  = h + (size_t)ROWS * 512;             // ROWS*512
    float* qkv = hn + (size_t)ROWS * 512;            // ROWS*2048 (qkv then ffn-up)
    float* g   = qkv + (size_t)ROWS * 2048;          // ROWS*1024

    build_h_k<<<(NB * SS * DD) / 256, 256, 0, stream>>>(x, rt, h);

    for (int i = 0; i < 2; ++i) {
        const float* aw = attn_w      + (size_t)i * 512 * 1536;
        const float* ow = attn_o_w    + (size_t)i * 512 * 512;
        const float* uw = ffn_up_w    + (size_t)i * 512 * 2048;
        const float* dw = ffn_down_w  + (size_t)i * 1024 * 512;
        const float* anw = attn_norm_w + (size_t)i * 512;
        const float* fnw = ffn_norm_w  + (size_t)i * 512;

        rmsnorm_k<<<ROWS, 256, 0, stream>>>(h, anw, hn);
        gemm64_k<0><<<dim3(1536 / 64, ROWS / 64), 256, 0, stream>>>(hn, aw, qkv, 512, 1536);
        rope_k<<<(NB * SS * NH * 32) / 256, 256, 0, stream>>>(qkv);
        attn_k<<<NB * NH * SS, 64, 0, stream>>>(qkv, doc, hn);   // o overwrites hn
        gemm64_k<1><<<dim3(512 / 64, ROWS / 64), 256, 0, stream>>>(hn, ow, h, 512, 512);
        rmsnorm_k<<<ROWS, 256, 0, stream>>>(h, fnw, hn);
        gemm64_k<0><<<dim3(2048 / 64, ROWS / 64), 256, 0, stream>>>(hn, uw, qkv, 512, 2048);
        silu_k<<<(ROWS * FFH) / 256, 256, 0, stream>>>(qkv, g);
        gemm64_k<1><<<dim3(512 / 64, ROWS / 64), 256, 0, stream>>>(g, dw, h, 1024, 512);
    }

    extract_k<<<(NB * LB * DD) / 256, 256, 0, stream>>>(h, out);
}

// Round 2
// 941.466 us; speedup vs baseline: 4.6432x; 4.6432x over previous
//
#include <hip/hip_runtime.h>
#include <math.h>

#define NB 2          // batch
#define LB 32         // blocks
#define BLKN 64       // block size
#define MM 65         // block + router
#define SS (LB*MM)    // 2080
#define DD 512
#define NH 8
#define HD 64
#define FFH 1024
#define ROWS (NB*SS)  // 4160
#define NEGINF -3.402823466e38f

typedef __attribute__((ext_vector_type(8))) short bf16x8;
typedef __attribute__((ext_vector_type(4))) float f32x4;

__device__ __forceinline__ unsigned short f2bf(float f) {
    union { float f; unsigned u; } v; v.f = f;
    unsigned r = (v.u + 0x7FFFu + ((v.u >> 16) & 1u)) >> 16;   // RNE
    return (unsigned short)r;
}

// ---------------- build h: insert router token ----------------
__global__ void build_h_k(const float* __restrict__ x, const float* __restrict__ rt,
                          float* __restrict__ h) {
    int idx = blockIdx.x * blockDim.x + threadIdx.x;   // over NB*SS*DD
    int d = idx % DD;
    int s = (idx / DD) % SS;
    int b = idx / (DD * SS);
    int l = s / MM, j = s % MM;
    float v = (j < BLKN) ? x[((size_t)(b * LB + l) * BLKN + j) * DD + d] : rt[d];
    h[idx] = v;
}

// ---------------- rmsnorm ----------------
__global__ __launch_bounds__(256) void rmsnorm_k(const float* __restrict__ in,
                                                 const float* __restrict__ w,
                                                 float* __restrict__ out) {
    int row = blockIdx.x;
    const float* xr = in + (size_t)row * DD;
    float* orow = out + (size_t)row * DD;
    int t = threadIdx.x;
    float v0 = xr[t], v1 = xr[t + 256];
    float ss = v0 * v0 + v1 * v1;
    #pragma unroll
    for (int off = 32; off; off >>= 1) ss += __shfl_xor(ss, off);
    __shared__ float red[4];
    if ((t & 63) == 0) red[t >> 6] = ss;
    __syncthreads();
    float tot = red[0] + red[1] + red[2] + red[3];
    float r = rsqrtf(tot * (1.0f / 512.0f) + 1e-5f);
    orow[t] = v0 * r * w[t];
    orow[t + 256] = v1 * r * w[t + 256];
}

// ---------------- tiled f32 GEMM: C[ROWS,N] (+)= A[ROWS,K] @ W[K,N] ----------------
template <int ADD>
__global__ __launch_bounds__(256) void gemm64_k(const float* __restrict__ A,
                                                const float* __restrict__ W,
                                                float* __restrict__ C, int K, int N) {
    __shared__ float As[16][68];
    __shared__ float Bs[16][68];
    int t = threadIdx.x;
    int tx = t & 15, ty = t >> 4;
    int rowBase = blockIdx.y * 64, colBase = blockIdx.x * 64;
    float acc[4][4];
    #pragma unroll
    for (int i = 0; i < 4; ++i)
        #pragma unroll
        for (int j = 0; j < 4; ++j) acc[i][j] = 0.0f;

    for (int k0 = 0; k0 < K; k0 += 16) {
        {   // A tile: 64 rows x 16 k
            int r = t >> 2;
            int kk = (t & 3) * 4;
            const float4 a4 = *(const float4*)(A + (size_t)(rowBase + r) * K + k0 + kk);
            As[kk + 0][r] = a4.x; As[kk + 1][r] = a4.y;
            As[kk + 2][r] = a4.z; As[kk + 3][r] = a4.w;
        }
        {   // B tile: 16 k x 64 cols
            int kk = t >> 4;
            int c = (t & 15) * 4;
            *(float4*)(&Bs[kk][c]) = *(const float4*)(W + (size_t)(k0 + kk) * N + colBase + c);
        }
        __syncthreads();
        #pragma unroll
        for (int kk = 0; kk < 16; ++kk) {
            float4 a = *(const float4*)(&As[kk][ty * 4]);
            float4 b = *(const float4*)(&Bs[kk][tx * 4]);
            acc[0][0] += a.x * b.x; acc[0][1] += a.x * b.y; acc[0][2] += a.x * b.z; acc[0][3] += a.x * b.w;
            acc[1][0] += a.y * b.x; acc[1][1] += a.y * b.y; acc[1][2] += a.y * b.z; acc[1][3] += a.y * b.w;
            acc[2][0] += a.z * b.x; acc[2][1] += a.z * b.y; acc[2][2] += a.z * b.z; acc[2][3] += a.z * b.w;
            acc[3][0] += a.w * b.x; acc[3][1] += a.w * b.y; acc[3][2] += a.w * b.z; acc[3][3] += a.w * b.w;
        }
        __syncthreads();
    }
    #pragma unroll
    for (int i = 0; i < 4; ++i) {
        float* crow = C + (size_t)(rowBase + ty * 4 + i) * N + colBase + tx * 4;
        if (ADD) {
            float4 c = *(const float4*)crow;
            c.x += acc[i][0]; c.y += acc[i][1]; c.z += acc[i][2]; c.w += acc[i][3];
            *(float4*)crow = c;
        } else {
            float4 c = make_float4(acc[i][0], acc[i][1], acc[i][2], acc[i][3]);
            *(float4*)crow = c;
        }
    }
}

// ---------------- rotary on q and k (in-place in qkv) ----------------
__global__ void rope_k(float* __restrict__ qkv) {
    int idx = blockIdx.x * blockDim.x + threadIdx.x;  // NB*SS*NH*32
    int j = idx & 31;
    int h = (idx >> 5) & 7;
    int s = (idx >> 8) % SS;
    int b = idx / (256 * SS);
    float inv = powf(1e-4f, (float)j * (1.0f / 32.0f));
    float fr = (float)s * inv;
    float c = cosf(fr), sn = sinf(fr);
    size_t base = ((size_t)(b * SS + s)) * 1536 + h * 64 + j;
    float q1 = qkv[base], q2 = qkv[base + 32];
    qkv[base] = q1 * c + q2 * sn;
    qkv[base + 32] = -q1 * sn + q2 * c;
    float k1 = qkv[base + 512], k2 = qkv[base + 544];
    qkv[base + 512] = k1 * c + k2 * sn;
    qkv[base + 544] = -k1 * sn + k2 * c;
}

// ---------------- flash attention, bf16 MFMA ----------------
// one WG (512 thr = 8 waves) per (b,h,l); waves 0..4 own M-tiles of 16 q rows
#define QROWS 80
#define KT 64
#define LDP 72   // padded bf16 row length (144 B: 16B-aligned, 2-way bank spread)

__global__ __launch_bounds__(512) void attn_mfma_k(const float* __restrict__ qkv,
                                                   const int* __restrict__ doc,
                                                   float* __restrict__ o) {
    __shared__ unsigned short Qs[QROWS][LDP];
    __shared__ unsigned short Ks[KT][LDP];
    __shared__ unsigned short Vt[HD][LDP];       // transposed: [d][key]
    __shared__ unsigned short Ps[5][16][LDP];    // wave-private P tiles
    __shared__ int docq[QROWS];
    __shared__ int dock[KT];

    int idx = blockIdx.x;
    int l = 31 - (idx >> 4);          // big key-ranges dispatched first
    int b = (idx >> 3) & 1;
    int h = idx & 7;
    int t = threadIdx.x;
    int lane = t & 63;
    int wv = t >> 6;

    size_t qkvBase = (size_t)b * SS * 1536;
    int rowq0 = l * MM;
    int kmax = (l + 1) * MM;

    // stage Q (rotary already applied): 80 rows x 64 d, rows >= 65 zero
    #pragma unroll
    for (int i = 0; i < 10; ++i) {
        int e = t + 512 * i;
        int row = e >> 6, d = e & 63;
        float v = 0.0f;
        if (row < MM) v = qkv[qkvBase + (size_t)(rowq0 + row) * 1536 + h * 64 + d];
        Qs[row][d] = f2bf(v);
    }
    if (t < QROWS) docq[t] = (t < MM) ? doc[b * SS + rowq0 + t] : -999999;

    const int mt = wv;
    const bool mtv = (wv < 5);
    const int g = lane >> 4;
    const int c = lane & 15;

    f32x4 oacc[4];
    float m_[4], l_[4];
    #pragma unroll
    for (int nt = 0; nt < 4; ++nt) { f32x4 z = {0,0,0,0}; oacc[nt] = z; }
    #pragma unroll
    for (int j = 0; j < 4; ++j) { m_[j] = -1e30f; l_[j] = 0.0f; }

    int nkt = (kmax + KT - 1) >> 6;
    for (int kt = 0; kt < nkt; ++kt) {
        int kbase = kt << 6;
        __syncthreads();
        {   // stage K row-major + V transposed (f32 -> bf16)
            int key = t >> 3;
            int d0 = (t & 7) * 8;
            int kg = kbase + key;
            float4 a0, a1, b0, b1;
            if (kg < kmax) {
                const float* kr = &qkv[qkvBase + (size_t)kg * 1536 + 512 + h * 64 + d0];
                a0 = *(const float4*)kr; a1 = *(const float4*)(kr + 4);
                const float* vr = kr + 512;
                b0 = *(const float4*)vr; b1 = *(const float4*)(vr + 4);
            } else {
                a0 = a1 = b0 = b1 = make_float4(0, 0, 0, 0);
            }
            unsigned short kb[8] = {f2bf(a0.x), f2bf(a0.y), f2bf(a0.z), f2bf(a0.w),
                                    f2bf(a1.x), f2bf(a1.y), f2bf(a1.z), f2bf(a1.w)};
            *(bf16x8*)&Ks[key][d0] = *(const bf16x8*)kb;
            unsigned short vb[8] = {f2bf(b0.x), f2bf(b0.y), f2bf(b0.z), f2bf(b0.w),
                                    f2bf(b1.x), f2bf(b1.y), f2bf(b1.z), f2bf(b1.w)};
            #pragma unroll
            for (int jj = 0; jj < 8; ++jj) Vt[d0 + jj][key] = vb[jj];
        }
        if (t < KT) {
            int kg = kbase + t;
            dock[t] = (kg < kmax) ? doc[b * SS + kg] : -1000000;
        }
        __syncthreads();

        if (mtv) {
            // ---- S = Q K^T (4 key-subtiles x 2 K-halves) ----
            f32x4 s[4];
            #pragma unroll
            for (int sub = 0; sub < 4; ++sub) {
                f32x4 acc = {0, 0, 0, 0};
                #pragma unroll
                for (int hf = 0; hf < 2; ++hf) {
                    bf16x8 af = *(const bf16x8*)&Qs[mt * 16 + c][hf * 32 + g * 8];
                    bf16x8 bk = *(const bf16x8*)&Ks[sub * 16 + c][hf * 32 + g * 8];
                    acc = __builtin_amdgcn_mfma_f32_16x16x32_bf16(af, bk, acc, 0, 0, 0);
                }
                s[sub] = acc;
            }
            // ---- mask + scale ----
            int dq[4];
            #pragma unroll
            for (int j = 0; j < 4; ++j) dq[j] = docq[mt * 16 + g * 4 + j];
            #pragma unroll
            for (int sub = 0; sub < 4; ++sub) {
                int dk = dock[sub * 16 + c];
                #pragma unroll
                for (int j = 0; j < 4; ++j)
                    s[sub][j] = (dq[j] == dk) ? s[sub][j] * 0.125f : -1e30f;
            }
            // ---- tile row-max (over 64 keys) ----
            float mx[4];
            #pragma unroll
            for (int j = 0; j < 4; ++j)
                mx[j] = fmaxf(fmaxf(s[0][j], s[1][j]), fmaxf(s[2][j], s[3][j]));
            #pragma unroll
            for (int off = 1; off < 16; off <<= 1)
                #pragma unroll
                for (int j = 0; j < 4; ++j) mx[j] = fmaxf(mx[j], __shfl_xor(mx[j], off));
            // ---- online softmax update ----
            float mn[4], sc[4], rs[4];
            #pragma unroll
            for (int j = 0; j < 4; ++j) {
                mn[j] = fmaxf(m_[j], mx[j]);
                sc[j] = __expf(m_[j] - mn[j]);
                m_[j] = mn[j];
                rs[j] = 0.0f;
            }
            #pragma unroll
            for (int sub = 0; sub < 4; ++sub)
                #pragma unroll
                for (int j = 0; j < 4; ++j) {
                    float p = __expf(s[sub][j] - mn[j]);
                    rs[j] += p;
                    Ps[wv][g * 4 + j][sub * 16 + c] = f2bf(p);
                }
            #pragma unroll
            for (int off = 1; off < 16; off <<= 1)
                #pragma unroll
                for (int j = 0; j < 4; ++j) rs[j] += __shfl_xor(rs[j], off);
            #pragma unroll
            for (int j = 0; j < 4; ++j) l_[j] = l_[j] * sc[j] + rs[j];
            #pragma unroll
            for (int nt = 0; nt < 4; ++nt)
                #pragma unroll
                for (int j = 0; j < 4; ++j) oacc[nt][j] *= sc[j];
            // ---- O += P V ----
            #pragma unroll
            for (int hf = 0; hf < 2; ++hf) {
                bf16x8 af = *(const bf16x8*)&Ps[wv][c][hf * 32 + g * 8];
                #pragma unroll
                for (int nt = 0; nt < 4; ++nt) {
                    bf16x8 bv = *(const bf16x8*)&Vt[nt * 16 + c][hf * 32 + g * 8];
                    oacc[nt] = __builtin_amdgcn_mfma_f32_16x16x32_bf16(af, bv, oacc[nt], 0, 0, 0);
                }
            }
        }
    }

    if (mtv) {
        #pragma unroll
        for (int j = 0; j < 4; ++j) {
            int row = mt * 16 + g * 4 + j;
            if (row < MM) {
                float invl = 1.0f / l_[j];
                #pragma unroll
                for (int nt = 0; nt < 4; ++nt)
                    o[(size_t)(b * SS + rowq0 + row) * DD + h * 64 + nt * 16 + c] =
                        oacc[nt][j] * invl;
            }
        }
    }
}

// ---------------- SwiGLU ----------------
__global__ void silu_k(const float* __restrict__ u, float* __restrict__ g) {
    int idx = blockIdx.x * blockDim.x + threadIdx.x;  // ROWS*FFH
    int j = idx % FFH;
    size_t r = idx / FFH;
    float a = u[r * 2048 + j];
    float b = u[r * 2048 + 1024 + j];
    g[idx] = (a / (1.0f + expf(-a))) * b;
}

// ---------------- extract router slots ----------------
__global__ void extract_k(const float* __restrict__ h, float* __restrict__ out) {
    int idx = blockIdx.x * blockDim.x + threadIdx.x;  // NB*LB*DD
    int d = idx % DD;
    int l = (idx / DD) % LB;
    int b = idx / (DD * LB);
    out[idx] = h[((size_t)(b * SS + l * MM + BLKN)) * DD + d];
}

extern "C" void kernel_launch(void* const* d_in, const int* in_sizes, int n_in,
                              void* d_out, int out_size, void* d_ws, size_t ws_size,
                              hipStream_t stream) {
    const float* x           = (const float*)d_in[0];
    const int*   doc         = (const int*)d_in[1];
    const float* rt          = (const float*)d_in[2];
    const float* attn_w      = (const float*)d_in[3];
    const float* attn_o_w    = (const float*)d_in[4];
    const float* ffn_up_w    = (const float*)d_in[5];
    const float* ffn_down_w  = (const float*)d_in[6];
    const float* attn_norm_w = (const float*)d_in[7];
    const float* ffn_norm_w  = (const float*)d_in[8];
    float* out = (float*)d_out;

    float* h   = (float*)d_ws;                       // ROWS*512
    float* hn  = h + (size_t)ROWS * 512;             // ROWS*512
    float* qkv = hn + (size_t)ROWS * 512;            // ROWS*2048 (qkv then ffn-up)
    float* g   = qkv + (size_t)ROWS * 2048;          // ROWS*1024

    build_h_k<<<(NB * SS * DD) / 256, 256, 0, stream>>>(x, rt, h);

    for (int i = 0; i < 2; ++i) {
        const float* aw = attn_w      + (size_t)i * 512 * 1536;
        const float* ow = attn_o_w    + (size_t)i * 512 * 512;
        const float* uw = ffn_up_w    + (size_t)i * 512 * 2048;
        const float* dw = ffn_down_w  + (size_t)i * 1024 * 512;
        const float* anw = attn_norm_w + (size_t)i * 512;
        const float* fnw = ffn_norm_w  + (size_t)i * 512;

        rmsnorm_k<<<ROWS, 256, 0, stream>>>(h, anw, hn);
        gemm64_k<0><<<dim3(1536 / 64, ROWS / 64), 256, 0, stream>>>(hn, aw, qkv, 512, 1536);
        rope_k<<<(NB * SS * NH * 32) / 256, 256, 0, stream>>>(qkv);
        attn_mfma_k<<<512, 512, 0, stream>>>(qkv, doc, hn);      // o overwrites hn
        gemm64_k<1><<<dim3(512 / 64, ROWS / 64), 256, 0, stream>>>(hn, ow, h, 512, 512);
        rmsnorm_k<<<ROWS, 256, 0, stream>>>(h, fnw, hn);
        gemm64_k<0><<<dim3(2048 / 64, ROWS / 64), 256, 0, stream>>>(hn, uw, qkv, 512, 2048);
        silu_k<<<(ROWS * FFH) / 256, 256, 0, stream>>>(qkv, g);
        gemm64_k<1><<<dim3(512 / 64, ROWS / 64), 256, 0, stream>>>(g, dw, h, 1024, 512);
    }

    extract_k<<<(NB * LB * DD) / 256, 256, 0, stream>>>(h, out);
}

// Round 3
// 394.156 us; speedup vs baseline: 11.0905x; 2.3886x over previous
//
#include <hip/hip_runtime.h>
#include <math.h>

#define NB 2          // batch
#define LB 32         // blocks
#define BLKN 64       // block size
#define MM 65         // block + router
#define SS (LB*MM)    // 2080
#define DD 512
#define NH 8
#define HD 64
#define FFH 1024
#define ROWS (NB*SS)  // 4160
#define NEGINF -3.402823466e38f
#define WT_LS 2621440 // bf16 elems per layer of transposed weights

typedef __attribute__((ext_vector_type(8))) short bf16x8;
typedef __attribute__((ext_vector_type(4))) float f32x4;

__device__ __forceinline__ unsigned short f2bf(float f) {
    union { float f; unsigned u; } v; v.f = f;
    unsigned r = (v.u + 0x7FFFu + ((v.u >> 16) & 1u)) >> 16;   // RNE
    return (unsigned short)r;
}

__device__ __forceinline__ void gload_lds16(const unsigned short* g, unsigned short* l) {
    __builtin_amdgcn_global_load_lds((const __attribute__((address_space(1))) unsigned int*)g,
                                     (__attribute__((address_space(3))) unsigned int*)l,
                                     16, 0, 0);
}

// ---------------- build h: insert router token ----------------
__global__ void build_h_k(const float* __restrict__ x, const float* __restrict__ rt,
                          float* __restrict__ h) {
    int idx = blockIdx.x * blockDim.x + threadIdx.x;   // over NB*SS*DD
    int d = idx % DD;
    int s = (idx / DD) % SS;
    int b = idx / (DD * SS);
    int l = s / MM, j = s % MM;
    float v = (j < BLKN) ? x[((size_t)(b * LB + l) * BLKN + j) * DD + d] : rt[d];
    h[idx] = v;
}

// ---------------- rmsnorm -> bf16 ----------------
__global__ __launch_bounds__(256) void rmsnorm_k(const float* __restrict__ in,
                                                 const float* __restrict__ w,
                                                 unsigned short* __restrict__ out) {
    int row = blockIdx.x;
    const float* xr = in + (size_t)row * DD;
    unsigned short* orow = out + (size_t)row * DD;
    int t = threadIdx.x;
    float v0 = xr[t], v1 = xr[t + 256];
    float ss = v0 * v0 + v1 * v1;
    #pragma unroll
    for (int off = 32; off; off >>= 1) ss += __shfl_xor(ss, off);
    __shared__ float red[4];
    if ((t & 63) == 0) red[t >> 6] = ss;
    __syncthreads();
    float tot = red[0] + red[1] + red[2] + red[3];
    float r = rsqrtf(tot * (1.0f / 512.0f) + 1e-5f);
    orow[t] = f2bf(v0 * r * w[t]);
    orow[t + 256] = f2bf(v1 * r * w[t + 256]);
}

// ---------------- weight transpose + bf16 convert: W[K,N] f32 -> Wt[N,K] bf16 ----
__global__ __launch_bounds__(256) void wtrans_k(const float* __restrict__ W,
                                                unsigned short* __restrict__ Wt,
                                                int K, int N) {
    __shared__ unsigned short T[64][66];
    int n0 = blockIdx.x * 64, k0 = blockIdx.y * 64;
    int t = threadIdx.x;
    #pragma unroll
    for (int i = 0; i < 16; ++i) {
        int e = t + i * 256;
        int r = e >> 6, c = e & 63;
        T[r][c] = f2bf(W[(size_t)(k0 + r) * N + n0 + c]);
    }
    __syncthreads();
    #pragma unroll
    for (int i = 0; i < 16; ++i) {
        int e = t + i * 256;
        int r = e >> 6, c = e & 63;   // r = n-row, c = k-col
        Wt[(size_t)(n0 + r) * K + k0 + c] = T[c][r];
    }
}

// ---------------- bf16 MFMA GEMM: C[ROWS,N] (+)= A[ROWS,K] @ Wt[N,K]^T ----------
// 256 thr = 4 waves; WG tile 64(M) x 128(N); BK=64; XOR-swizzled LDS.
template <int ADD>
__global__ __launch_bounds__(256) void gemm_bf16_k(const unsigned short* __restrict__ A,
                                                   const unsigned short* __restrict__ Wt,
                                                   float* __restrict__ C,
                                                   int K, int N) {
    __shared__ unsigned short As[64 * 64];    // 8 KB, swizzled rows of 128B
    __shared__ unsigned short Bs[128 * 64];   // 16 KB
    int t = threadIdx.x;
    int lane = t & 63, wv = t >> 6;
    int wm = wv >> 1, wn = wv & 1;
    int rowBase = blockIdx.y * 64, colBase = blockIdx.x * 128;
    int c = lane & 15, g = lane >> 4;
    int sw = (c & 7) << 4;

    f32x4 acc[2][4];
    #pragma unroll
    for (int mt = 0; mt < 2; ++mt)
        #pragma unroll
        for (int nt = 0; nt < 4; ++nt) { f32x4 z = {0, 0, 0, 0}; acc[mt][nt] = z; }

    for (int k0 = 0; k0 < K; k0 += 64) {
        __syncthreads();
        // stage A (64 rows x 64 k): inverse-swizzled global source, linear LDS dest
        #pragma unroll
        for (int i = 0; i < 2; ++i) {
            int e0 = (i * 4 + wv) * 64;
            int e = e0 + lane;
            int row = e >> 3;
            int kb = ((e & 7) << 4) ^ ((row & 7) << 4);
            gload_lds16(A + (size_t)(rowBase + row) * K + k0 + (kb >> 1), &As[e0 * 8]);
        }
        // stage B (128 n-rows x 64 k)
        #pragma unroll
        for (int i = 0; i < 4; ++i) {
            int e0 = (i * 4 + wv) * 64;
            int e = e0 + lane;
            int row = e >> 3;
            int kb = ((e & 7) << 4) ^ ((row & 7) << 4);
            gload_lds16(Wt + (size_t)(colBase + row) * K + k0 + (kb >> 1), &Bs[e0 * 8]);
        }
        __syncthreads();   // drains vmcnt(0) too

        bf16x8 af[2][2], bfr[4][2];
        #pragma unroll
        for (int mt = 0; mt < 2; ++mt)
            #pragma unroll
            for (int hf = 0; hf < 2; ++hf)
                af[mt][hf] = *(const bf16x8*)
                    &As[((wm * 32 + mt * 16 + c) * 128 + ((hf * 64 + g * 16) ^ sw)) >> 1];
        #pragma unroll
        for (int nt = 0; nt < 4; ++nt)
            #pragma unroll
            for (int hf = 0; hf < 2; ++hf)
                bfr[nt][hf] = *(const bf16x8*)
                    &Bs[((wn * 64 + nt * 16 + c) * 128 + ((hf * 64 + g * 16) ^ sw)) >> 1];
        #pragma unroll
        for (int mt = 0; mt < 2; ++mt)
            #pragma unroll
            for (int nt = 0; nt < 4; ++nt) {
                acc[mt][nt] = __builtin_amdgcn_mfma_f32_16x16x32_bf16(af[mt][0], bfr[nt][0], acc[mt][nt], 0, 0, 0);
                acc[mt][nt] = __builtin_amdgcn_mfma_f32_16x16x32_bf16(af[mt][1], bfr[nt][1], acc[mt][nt], 0, 0, 0);
            }
    }

    #pragma unroll
    for (int mt = 0; mt < 2; ++mt)
        #pragma unroll
        for (int j = 0; j < 4; ++j) {
            int row = rowBase + wm * 32 + mt * 16 + g * 4 + j;
            float* cr = C + (size_t)row * N + colBase + wn * 64 + c;
            #pragma unroll
            for (int nt = 0; nt < 4; ++nt) {
                if (ADD) cr[nt * 16] += acc[mt][nt][j];
                else     cr[nt * 16] = acc[mt][nt][j];
            }
        }
}

// ---------------- rotary on q and k (in-place in qkv) ----------------
__global__ void rope_k(float* __restrict__ qkv) {
    int idx = blockIdx.x * blockDim.x + threadIdx.x;  // NB*SS*NH*32
    int j = idx & 31;
    int h = (idx >> 5) & 7;
    int s = (idx >> 8) % SS;
    int b = idx / (256 * SS);
    float inv = powf(1e-4f, (float)j * (1.0f / 32.0f));
    float fr = (float)s * inv;
    float c = cosf(fr), sn = sinf(fr);
    size_t base = ((size_t)(b * SS + s)) * 1536 + h * 64 + j;
    float q1 = qkv[base], q2 = qkv[base + 32];
    qkv[base] = q1 * c + q2 * sn;
    qkv[base + 32] = -q1 * sn + q2 * c;
    float k1 = qkv[base + 512], k2 = qkv[base + 544];
    qkv[base + 512] = k1 * c + k2 * sn;
    qkv[base + 544] = -k1 * sn + k2 * c;
}

// ---------------- flash attention, bf16 MFMA ----------------
#define QROWS 80
#define KT 64
#define LDP 72

__global__ __launch_bounds__(512) void attn_mfma_k(const float* __restrict__ qkv,
                                                   const int* __restrict__ doc,
                                                   unsigned short* __restrict__ o) {
    __shared__ unsigned short Qs[QROWS][LDP];
    __shared__ unsigned short Ks[KT][LDP];
    __shared__ unsigned short Vt[HD][LDP];       // transposed: [d][key]
    __shared__ unsigned short Ps[5][16][LDP];    // wave-private P tiles
    __shared__ int docq[QROWS];
    __shared__ int dock[KT];

    int idx = blockIdx.x;
    int l = 31 - (idx >> 4);          // big key-ranges dispatched first
    int b = (idx >> 3) & 1;
    int h = idx & 7;
    int t = threadIdx.x;
    int lane = t & 63;
    int wv = t >> 6;

    size_t qkvBase = (size_t)b * SS * 1536;
    int rowq0 = l * MM;
    int kmax = (l + 1) * MM;

    #pragma unroll
    for (int i = 0; i < 10; ++i) {
        int e = t + 512 * i;
        int row = e >> 6, d = e & 63;
        float v = 0.0f;
        if (row < MM) v = qkv[qkvBase + (size_t)(rowq0 + row) * 1536 + h * 64 + d];
        Qs[row][d] = f2bf(v);
    }
    if (t < QROWS) docq[t] = (t < MM) ? doc[b * SS + rowq0 + t] : -999999;

    const int mt = wv;
    const bool mtv = (wv < 5);
    const int g = lane >> 4;
    const int c = lane & 15;

    f32x4 oacc[4];
    float m_[4], l_[4];
    #pragma unroll
    for (int nt = 0; nt < 4; ++nt) { f32x4 z = {0,0,0,0}; oacc[nt] = z; }
    #pragma unroll
    for (int j = 0; j < 4; ++j) { m_[j] = -1e30f; l_[j] = 0.0f; }

    int nkt = (kmax + KT - 1) >> 6;
    for (int kt = 0; kt < nkt; ++kt) {
        int kbase = kt << 6;
        __syncthreads();
        {
            int key = t >> 3;
            int d0 = (t & 7) * 8;
            int kg = kbase + key;
            float4 a0, a1, b0, b1;
            if (kg < kmax) {
                const float* kr = &qkv[qkvBase + (size_t)kg * 1536 + 512 + h * 64 + d0];
                a0 = *(const float4*)kr; a1 = *(const float4*)(kr + 4);
                const float* vr = kr + 512;
                b0 = *(const float4*)vr; b1 = *(const float4*)(vr + 4);
            } else {
                a0 = a1 = b0 = b1 = make_float4(0, 0, 0, 0);
            }
            unsigned short kb[8] = {f2bf(a0.x), f2bf(a0.y), f2bf(a0.z), f2bf(a0.w),
                                    f2bf(a1.x), f2bf(a1.y), f2bf(a1.z), f2bf(a1.w)};
            *(bf16x8*)&Ks[key][d0] = *(const bf16x8*)kb;
            unsigned short vb[8] = {f2bf(b0.x), f2bf(b0.y), f2bf(b0.z), f2bf(b0.w),
                                    f2bf(b1.x), f2bf(b1.y), f2bf(b1.z), f2bf(b1.w)};
            #pragma unroll
            for (int jj = 0; jj < 8; ++jj) Vt[d0 + jj][key] = vb[jj];
        }
        if (t < KT) {
            int kg = kbase + t;
            dock[t] = (kg < kmax) ? doc[b * SS + kg] : -1000000;
        }
        __syncthreads();

        if (mtv) {
            f32x4 s[4];
            #pragma unroll
            for (int sub = 0; sub < 4; ++sub) {
                f32x4 acc = {0, 0, 0, 0};
                #pragma unroll
                for (int hf = 0; hf < 2; ++hf) {
                    bf16x8 af = *(const bf16x8*)&Qs[mt * 16 + c][hf * 32 + g * 8];
                    bf16x8 bk = *(const bf16x8*)&Ks[sub * 16 + c][hf * 32 + g * 8];
                    acc = __builtin_amdgcn_mfma_f32_16x16x32_bf16(af, bk, acc, 0, 0, 0);
                }
                s[sub] = acc;
            }
            int dq[4];
            #pragma unroll
            for (int j = 0; j < 4; ++j) dq[j] = docq[mt * 16 + g * 4 + j];
            #pragma unroll
            for (int sub = 0; sub < 4; ++sub) {
                int dk = dock[sub * 16 + c];
                #pragma unroll
                for (int j = 0; j < 4; ++j)
                    s[sub][j] = (dq[j] == dk) ? s[sub][j] * 0.125f : -1e30f;
            }
            float mx[4];
            #pragma unroll
            for (int j = 0; j < 4; ++j)
                mx[j] = fmaxf(fmaxf(s[0][j], s[1][j]), fmaxf(s[2][j], s[3][j]));
            #pragma unroll
            for (int off = 1; off < 16; off <<= 1)
                #pragma unroll
                for (int j = 0; j < 4; ++j) mx[j] = fmaxf(mx[j], __shfl_xor(mx[j], off));
            float mn[4], sc[4], rs[4];
            #pragma unroll
            for (int j = 0; j < 4; ++j) {
                mn[j] = fmaxf(m_[j], mx[j]);
                sc[j] = __expf(m_[j] - mn[j]);
                m_[j] = mn[j];
                rs[j] = 0.0f;
            }
            #pragma unroll
            for (int sub = 0; sub < 4; ++sub)
                #pragma unroll
                for (int j = 0; j < 4; ++j) {
                    float p = __expf(s[sub][j] - mn[j]);
                    rs[j] += p;
                    Ps[wv][g * 4 + j][sub * 16 + c] = f2bf(p);
                }
            #pragma unroll
            for (int off = 1; off < 16; off <<= 1)
                #pragma unroll
                for (int j = 0; j < 4; ++j) rs[j] += __shfl_xor(rs[j], off);
            #pragma unroll
            for (int j = 0; j < 4; ++j) l_[j] = l_[j] * sc[j] + rs[j];
            #pragma unroll
            for (int nt = 0; nt < 4; ++nt)
                #pragma unroll
                for (int j = 0; j < 4; ++j) oacc[nt][j] *= sc[j];
            #pragma unroll
            for (int hf = 0; hf < 2; ++hf) {
                bf16x8 af = *(const bf16x8*)&Ps[wv][c][hf * 32 + g * 8];
                #pragma unroll
                for (int nt = 0; nt < 4; ++nt) {
                    bf16x8 bv = *(const bf16x8*)&Vt[nt * 16 + c][hf * 32 + g * 8];
                    oacc[nt] = __builtin_amdgcn_mfma_f32_16x16x32_bf16(af, bv, oacc[nt], 0, 0, 0);
                }
            }
        }
    }

    if (mtv) {
        #pragma unroll
        for (int j = 0; j < 4; ++j) {
            int row = mt * 16 + g * 4 + j;
            if (row < MM) {
                float invl = 1.0f / l_[j];
                #pragma unroll
                for (int nt = 0; nt < 4; ++nt)
                    o[(size_t)(b * SS + rowq0 + row) * DD + h * 64 + nt * 16 + c] =
                        f2bf(oacc[nt][j] * invl);
            }
        }
    }
}

// ---------------- SwiGLU -> bf16 ----------------
__global__ void silu_k(const float* __restrict__ u, unsigned short* __restrict__ g) {
    int idx = blockIdx.x * blockDim.x + threadIdx.x;  // ROWS*FFH
    int j = idx % FFH;
    size_t r = idx / FFH;
    float a = u[r * 2048 + j];
    float b = u[r * 2048 + 1024 + j];
    g[idx] = f2bf((a / (1.0f + expf(-a))) * b);
}

// ---------------- extract router slots ----------------
__global__ void extract_k(const float* __restrict__ h, float* __restrict__ out) {
    int idx = blockIdx.x * blockDim.x + threadIdx.x;  // NB*LB*DD
    int d = idx % DD;
    int l = (idx / DD) % LB;
    int b = idx / (DD * LB);
    out[idx] = h[((size_t)(b * SS + l * MM + BLKN)) * DD + d];
}

extern "C" void kernel_launch(void* const* d_in, const int* in_sizes, int n_in,
                              void* d_out, int out_size, void* d_ws, size_t ws_size,
                              hipStream_t stream) {
    const float* x           = (const float*)d_in[0];
    const int*   doc         = (const int*)d_in[1];
    const float* rt          = (const float*)d_in[2];
    const float* attn_w      = (const float*)d_in[3];
    const float* attn_o_w    = (const float*)d_in[4];
    const float* ffn_up_w    = (const float*)d_in[5];
    const float* ffn_down_w  = (const float*)d_in[6];
    const float* attn_norm_w = (const float*)d_in[7];
    const float* ffn_norm_w  = (const float*)d_in[8];
    float* out = (float*)d_out;

    float* h   = (float*)d_ws;                          // ROWS*512 f32
    float* qkv = h + (size_t)ROWS * 512;                // ROWS*2048 f32 (qkv / ffn-up)
    unsigned short* wt  = (unsigned short*)(qkv + (size_t)ROWS * 2048);  // 2*WT_LS bf16
    unsigned short* hnb = wt + (size_t)2 * WT_LS;       // ROWS*512 bf16
    unsigned short* ob  = hnb + (size_t)ROWS * 512;     // ROWS*512 bf16
    unsigned short* gb  = hnb;                          // aliases hnb+ob (ROWS*1024 bf16)

    build_h_k<<<(NB * SS * DD) / 256, 256, 0, stream>>>(x, rt, h);

    // pre-transpose weights -> bf16 [N][K]
    for (int i = 0; i < 2; ++i) {
        unsigned short* wl = wt + (size_t)i * WT_LS;
        wtrans_k<<<dim3(1536 / 64, 512 / 64), 256, 0, stream>>>(attn_w + (size_t)i * 512 * 1536, wl, 512, 1536);
        wtrans_k<<<dim3(512 / 64, 512 / 64), 256, 0, stream>>>(attn_o_w + (size_t)i * 512 * 512, wl + 786432, 512, 512);
        wtrans_k<<<dim3(2048 / 64, 512 / 64), 256, 0, stream>>>(ffn_up_w + (size_t)i * 512 * 2048, wl + 1048576, 512, 2048);
        wtrans_k<<<dim3(512 / 64, 1024 / 64), 256, 0, stream>>>(ffn_down_w + (size_t)i * 1024 * 512, wl + 2097152, 1024, 512);
    }

    for (int i = 0; i < 2; ++i) {
        unsigned short* wl = wt + (size_t)i * WT_LS;
        const float* anw = attn_norm_w + (size_t)i * 512;
        const float* fnw = ffn_norm_w  + (size_t)i * 512;

        rmsnorm_k<<<ROWS, 256, 0, stream>>>(h, anw, hnb);
        gemm_bf16_k<0><<<dim3(1536 / 128, ROWS / 64), 256, 0, stream>>>(hnb, wl, qkv, 512, 1536);
        rope_k<<<(NB * SS * NH * 32) / 256, 256, 0, stream>>>(qkv);
        attn_mfma_k<<<512, 512, 0, stream>>>(qkv, doc, ob);
        gemm_bf16_k<1><<<dim3(512 / 128, ROWS / 64), 256, 0, stream>>>(ob, wl + 786432, h, 512, 512);
        rmsnorm_k<<<ROWS, 256, 0, stream>>>(h, fnw, hnb);
        gemm_bf16_k<0><<<dim3(2048 / 128, ROWS / 64), 256, 0, stream>>>(hnb, wl + 1048576, qkv, 512, 2048);
        silu_k<<<(ROWS * FFH) / 256, 256, 0, stream>>>(qkv, gb);
        gemm_bf16_k<1><<<dim3(512 / 128, ROWS / 64), 256, 0, stream>>>(gb, wl + 2097152, h, 1024, 512);
    }

    extract_k<<<(NB * LB * DD) / 256, 256, 0, stream>>>(h, out);
}

// Round 4
// 371.166 us; speedup vs baseline: 11.7775x; 1.0619x over previous
//
#include <hip/hip_runtime.h>
#include <math.h>

#define NB 2          // batch
#define LB 32         // blocks
#define BLKN 64       // block size
#define MM 65         // block + router
#define SS (LB*MM)    // 2080
#define DD 512
#define NH 8
#define HD 64
#define FFH 1024
#define ROWS (NB*SS)  // 4160
#define WT_LS 2621440 // bf16 elems per layer of transposed weights

typedef __attribute__((ext_vector_type(8))) short bf16x8;
typedef __attribute__((ext_vector_type(4))) float f32x4;

__device__ __forceinline__ unsigned short f2bf(float f) {
    union { float f; unsigned u; } v; v.f = f;
    unsigned r = (v.u + 0x7FFFu + ((v.u >> 16) & 1u)) >> 16;   // RNE
    return (unsigned short)r;
}
__device__ __forceinline__ float bf2f(unsigned short u) {
    union { unsigned u; float f; } v; v.u = ((unsigned)u) << 16; return v.f;
}

__device__ __forceinline__ void gload_lds16(const unsigned short* g, unsigned short* l) {
    __builtin_amdgcn_global_load_lds((const __attribute__((address_space(1))) unsigned int*)g,
                                     (__attribute__((address_space(3))) unsigned int*)l,
                                     16, 0, 0);
}

// ---------------- build h: insert router token ----------------
__global__ void build_h_k(const float* __restrict__ x, const float* __restrict__ rt,
                          float* __restrict__ h) {
    int idx = blockIdx.x * blockDim.x + threadIdx.x;   // over NB*SS*DD
    int d = idx % DD;
    int s = (idx / DD) % SS;
    int b = idx / (DD * SS);
    int l = s / MM, j = s % MM;
    float v = (j < BLKN) ? x[((size_t)(b * LB + l) * BLKN + j) * DD + d] : rt[d];
    h[idx] = v;
}

// ---------------- rmsnorm -> bf16 ----------------
__global__ __launch_bounds__(256) void rmsnorm_k(const float* __restrict__ in,
                                                 const float* __restrict__ w,
                                                 unsigned short* __restrict__ out) {
    int row = blockIdx.x;
    const float* xr = in + (size_t)row * DD;
    unsigned short* orow = out + (size_t)row * DD;
    int t = threadIdx.x;
    float v0 = xr[t], v1 = xr[t + 256];
    float ss = v0 * v0 + v1 * v1;
    #pragma unroll
    for (int off = 32; off; off >>= 1) ss += __shfl_xor(ss, off);
    __shared__ float red[4];
    if ((t & 63) == 0) red[t >> 6] = ss;
    __syncthreads();
    float tot = red[0] + red[1] + red[2] + red[3];
    float r = rsqrtf(tot * (1.0f / 512.0f) + 1e-5f);
    orow[t] = f2bf(v0 * r * w[t]);
    orow[t + 256] = f2bf(v1 * r * w[t + 256]);
}

// ---------------- weight transpose + bf16 convert: W[K,N] f32 -> Wt[N,K] bf16 ----
__global__ __launch_bounds__(256) void wtrans_k(const float* __restrict__ W,
                                                unsigned short* __restrict__ Wt,
                                                int K, int N) {
    __shared__ unsigned short T[64][66];
    int n0 = blockIdx.x * 64, k0 = blockIdx.y * 64;
    int t = threadIdx.x;
    #pragma unroll
    for (int i = 0; i < 16; ++i) {
        int e = t + i * 256;
        int r = e >> 6, c = e & 63;
        T[r][c] = f2bf(W[(size_t)(k0 + r) * N + n0 + c]);
    }
    __syncthreads();
    #pragma unroll
    for (int i = 0; i < 16; ++i) {
        int e = t + i * 256;
        int r = e >> 6, c = e & 63;   // r = n-row, c = k-col
        Wt[(size_t)(n0 + r) * K + k0 + c] = T[c][r];
    }
}

// ---------------- bf16 MFMA GEMM: C[ROWS,N] (+)= A[ROWS,K] @ Wt[N,K]^T ----------
// 256 thr = 4 waves; WG tile 64(M) x 128(N); BK=64; XOR-swizzled LDS.
// OBF=1: write bf16 (no ADD). OBF=0: f32, optional ADD.
template <int ADD, int OBF>
__global__ __launch_bounds__(256) void gemm_bf16_k(const unsigned short* __restrict__ A,
                                                   const unsigned short* __restrict__ Wt,
                                                   void* __restrict__ Cp,
                                                   int K, int N) {
    __shared__ unsigned short As[64 * 64];    // 8 KB, swizzled rows of 128B
    __shared__ unsigned short Bs[128 * 64];   // 16 KB
    int t = threadIdx.x;
    int lane = t & 63, wv = t >> 6;
    int wm = wv >> 1, wn = wv & 1;
    int rowBase = blockIdx.y * 64, colBase = blockIdx.x * 128;
    int c = lane & 15, g = lane >> 4;
    int sw = (c & 7) << 4;

    f32x4 acc[2][4];
    #pragma unroll
    for (int mt = 0; mt < 2; ++mt)
        #pragma unroll
        for (int nt = 0; nt < 4; ++nt) { f32x4 z = {0, 0, 0, 0}; acc[mt][nt] = z; }

    for (int k0 = 0; k0 < K; k0 += 64) {
        __syncthreads();
        #pragma unroll
        for (int i = 0; i < 2; ++i) {
            int e0 = (i * 4 + wv) * 64;
            int e = e0 + lane;
            int row = e >> 3;
            int kb = ((e & 7) << 4) ^ ((row & 7) << 4);
            gload_lds16(A + (size_t)(rowBase + row) * K + k0 + (kb >> 1), &As[e0 * 8]);
        }
        #pragma unroll
        for (int i = 0; i < 4; ++i) {
            int e0 = (i * 4 + wv) * 64;
            int e = e0 + lane;
            int row = e >> 3;
            int kb = ((e & 7) << 4) ^ ((row & 7) << 4);
            gload_lds16(Wt + (size_t)(colBase + row) * K + k0 + (kb >> 1), &Bs[e0 * 8]);
        }
        __syncthreads();   // drains vmcnt(0) too

        bf16x8 af[2][2], bfr[4][2];
        #pragma unroll
        for (int mt = 0; mt < 2; ++mt)
            #pragma unroll
            for (int hf = 0; hf < 2; ++hf)
                af[mt][hf] = *(const bf16x8*)
                    &As[((wm * 32 + mt * 16 + c) * 128 + ((hf * 64 + g * 16) ^ sw)) >> 1];
        #pragma unroll
        for (int nt = 0; nt < 4; ++nt)
            #pragma unroll
            for (int hf = 0; hf < 2; ++hf)
                bfr[nt][hf] = *(const bf16x8*)
                    &Bs[((wn * 64 + nt * 16 + c) * 128 + ((hf * 64 + g * 16) ^ sw)) >> 1];
        #pragma unroll
        for (int mt = 0; mt < 2; ++mt)
            #pragma unroll
            for (int nt = 0; nt < 4; ++nt) {
                acc[mt][nt] = __builtin_amdgcn_mfma_f32_16x16x32_bf16(af[mt][0], bfr[nt][0], acc[mt][nt], 0, 0, 0);
                acc[mt][nt] = __builtin_amdgcn_mfma_f32_16x16x32_bf16(af[mt][1], bfr[nt][1], acc[mt][nt], 0, 0, 0);
            }
    }

    #pragma unroll
    for (int mt = 0; mt < 2; ++mt)
        #pragma unroll
        for (int j = 0; j < 4; ++j) {
            int row = rowBase + wm * 32 + mt * 16 + g * 4 + j;
            size_t off = (size_t)row * N + colBase + wn * 64 + c;
            if (OBF) {
                unsigned short* cr = (unsigned short*)Cp + off;
                #pragma unroll
                for (int nt = 0; nt < 4; ++nt) cr[nt * 16] = f2bf(acc[mt][nt][j]);
            } else {
                float* cr = (float*)Cp + off;
                #pragma unroll
                for (int nt = 0; nt < 4; ++nt) {
                    if (ADD) cr[nt * 16] += acc[mt][nt][j];
                    else     cr[nt * 16] = acc[mt][nt][j];
                }
            }
        }
}

// ---------------- rotary on q and k (in-place, bf16) ----------------
__global__ void rope_bf_k(unsigned short* __restrict__ qkv) {
    int idx = blockIdx.x * blockDim.x + threadIdx.x;  // NB*SS*NH*32
    int j = idx & 31;
    int h = (idx >> 5) & 7;
    int s = (idx >> 8) % SS;
    int b = idx / (256 * SS);
    float inv = powf(1e-4f, (float)j * (1.0f / 32.0f));
    float fr = (float)s * inv;
    float c, sn;
    __sincosf(fr, &sn, &c);
    size_t base = ((size_t)(b * SS + s)) * 1536 + h * 64 + j;
    float q1 = bf2f(qkv[base]), q2 = bf2f(qkv[base + 32]);
    qkv[base] = f2bf(q1 * c + q2 * sn);
    qkv[base + 32] = f2bf(-q1 * sn + q2 * c);
    float k1 = bf2f(qkv[base + 512]), k2 = bf2f(qkv[base + 544]);
    qkv[base + 512] = f2bf(k1 * c + k2 * sn);
    qkv[base + 544] = f2bf(-k1 * sn + k2 * c);
}

// ---------------- flash attention, bf16 MFMA, 5 waves ----------------
#define QR 80

__global__ __launch_bounds__(320) void attn_mfma_k(const unsigned short* __restrict__ qkv,
                                                   const int* __restrict__ doc,
                                                   unsigned short* __restrict__ o) {
    __shared__ unsigned short Qs[QR * 64];       // XOR-swizzled, 128B rows
    __shared__ unsigned short Ks[64 * 64];       // XOR-swizzled
    __shared__ unsigned short Vt[64][72];        // transposed [d][key], padded
    __shared__ unsigned short Ps[5][16][72];     // wave-private P tiles
    __shared__ int docq[QR];
    __shared__ int dock[64];

    int idx = blockIdx.x;
    int l = 31 - (idx >> 4);          // big key-ranges dispatched first
    int b = (idx >> 3) & 1;
    int h = idx & 7;
    int t = threadIdx.x;
    int lane = t & 63;
    int wv = t >> 6;

    const unsigned short* qb = qkv + (size_t)b * SS * 1536;
    int rowq0 = l * MM;
    int kmax = (l + 1) * MM;

    // stage Q swizzled: 640 x 16B over 320 threads (rows >= MM clamped, masked later)
    #pragma unroll
    for (int it = 0; it < 2; ++it) {
        int ebase = it * 320 + wv * 64;
        int e = ebase + lane;
        int row = e >> 3;
        int kb = ((e & 7) << 4) ^ ((row & 7) << 4);
        int gr = rowq0 + row; if (gr > SS - 1) gr = SS - 1;
        gload_lds16(qb + (size_t)gr * 1536 + h * 64 + (kb >> 1), &Qs[ebase * 8]);
    }
    if (t < QR) docq[t] = (t < MM) ? doc[b * SS + rowq0 + t] : -999999;

    const int mt = wv;
    const int g = lane >> 4;
    const int c = lane & 15;
    const int sw = (c & 7) << 4;

    f32x4 oacc[4];
    float m_[4], l_[4];
    #pragma unroll
    for (int nt = 0; nt < 4; ++nt) { f32x4 z = {0,0,0,0}; oacc[nt] = z; }
    #pragma unroll
    for (int j = 0; j < 4; ++j) { m_[j] = -1e30f; l_[j] = 0.0f; }

    int nkt = (kmax + 63) >> 6;
    for (int kt = 0; kt < nkt; ++kt) {
        int kbase = kt << 6;
        __syncthreads();
        // ---- stage K via gload_lds (swizzled): 512 x 16B ----
        {
            int ebase = wv * 64;
            int e = ebase + lane;
            int row = e >> 3;
            int kb = ((e & 7) << 4) ^ ((row & 7) << 4);
            int kg = kbase + row; if (kg > kmax - 1) kg = kmax - 1;
            gload_lds16(qb + (size_t)kg * 1536 + 512 + h * 64 + (kb >> 1), &Ks[ebase * 8]);
            if (wv < 3) {
                int eb2 = 320 + wv * 64;
                int e2 = eb2 + lane;
                int row2 = e2 >> 3;
                int kb2 = ((e2 & 7) << 4) ^ ((row2 & 7) << 4);
                int kg2 = kbase + row2; if (kg2 > kmax - 1) kg2 = kmax - 1;
                gload_lds16(qb + (size_t)kg2 * 1536 + 512 + h * 64 + (kb2 >> 1), &Ks[eb2 * 8]);
            }
        }
        // ---- stage V transposed: key = lane -> 2-way bank writes ----
        {
            int key = t & 63;
            int d0 = (t >> 6) * 8;
            int kg = kbase + key; if (kg > kmax - 1) kg = kmax - 1;
            bf16x8 v8 = *(const bf16x8*)(qb + (size_t)kg * 1536 + 1024 + h * 64 + d0);
            #pragma unroll
            for (int jj = 0; jj < 8; ++jj) Vt[d0 + jj][key] = ((unsigned short*)&v8)[jj];
            if (t < 192) {
                int e2 = 320 + t;
                int key2 = e2 & 63;
                int d02 = (e2 >> 6) * 8;
                int kg2 = kbase + key2; if (kg2 > kmax - 1) kg2 = kmax - 1;
                bf16x8 w8 = *(const bf16x8*)(qb + (size_t)kg2 * 1536 + 1024 + h * 64 + d02);
                #pragma unroll
                for (int jj = 0; jj < 8; ++jj) Vt[d02 + jj][key2] = ((unsigned short*)&w8)[jj];
            }
        }
        if (t < 64) dock[t] = (kbase + t < kmax) ? doc[b * SS + kbase + t] : -1000000;
        __syncthreads();

        // ---- S = Q K^T ----
        f32x4 s[4];
        #pragma unroll
        for (int sub = 0; sub < 4; ++sub) {
            f32x4 acc = {0, 0, 0, 0};
            #pragma unroll
            for (int hf = 0; hf < 2; ++hf) {
                bf16x8 af = *(const bf16x8*)
                    &Qs[((mt * 16 + c) * 128 + ((hf * 64 + g * 16) ^ sw)) >> 1];
                bf16x8 bk = *(const bf16x8*)
                    &Ks[((sub * 16 + c) * 128 + ((hf * 64 + g * 16) ^ sw)) >> 1];
                acc = __builtin_amdgcn_mfma_f32_16x16x32_bf16(af, bk, acc, 0, 0, 0);
            }
            s[sub] = acc;
        }
        // ---- mask + scale ----
        int dq[4];
        #pragma unroll
        for (int j = 0; j < 4; ++j) dq[j] = docq[mt * 16 + g * 4 + j];
        #pragma unroll
        for (int sub = 0; sub < 4; ++sub) {
            int dk = dock[sub * 16 + c];
            #pragma unroll
            for (int j = 0; j < 4; ++j)
                s[sub][j] = (dq[j] == dk) ? s[sub][j] * 0.125f : -1e30f;
        }
        // ---- tile row-max ----
        float mx[4];
        #pragma unroll
        for (int j = 0; j < 4; ++j)
            mx[j] = fmaxf(fmaxf(s[0][j], s[1][j]), fmaxf(s[2][j], s[3][j]));
        #pragma unroll
        for (int off = 1; off < 16; off <<= 1)
            #pragma unroll
            for (int j = 0; j < 4; ++j) mx[j] = fmaxf(mx[j], __shfl_xor(mx[j], off));
        // ---- online softmax update ----
        float mn[4], sc[4], rs[4];
        #pragma unroll
        for (int j = 0; j < 4; ++j) {
            mn[j] = fmaxf(m_[j], mx[j]);
            sc[j] = __expf(m_[j] - mn[j]);
            m_[j] = mn[j];
            rs[j] = 0.0f;
        }
        #pragma unroll
        for (int sub = 0; sub < 4; ++sub)
            #pragma unroll
            for (int j = 0; j < 4; ++j) {
                float p = __expf(s[sub][j] - mn[j]);
                rs[j] += p;
                Ps[wv][g * 4 + j][sub * 16 + c] = f2bf(p);
            }
        #pragma unroll
        for (int off = 1; off < 16; off <<= 1)
            #pragma unroll
            for (int j = 0; j < 4; ++j) rs[j] += __shfl_xor(rs[j], off);
        #pragma unroll
        for (int j = 0; j < 4; ++j) l_[j] = l_[j] * sc[j] + rs[j];
        #pragma unroll
        for (int nt = 0; nt < 4; ++nt)
            #pragma unroll
            for (int j = 0; j < 4; ++j) oacc[nt][j] *= sc[j];
        // ---- O += P V ----
        #pragma unroll
        for (int hf = 0; hf < 2; ++hf) {
            bf16x8 af = *(const bf16x8*)&Ps[wv][c][hf * 32 + g * 8];
            #pragma unroll
            for (int nt = 0; nt < 4; ++nt) {
                bf16x8 bv = *(const bf16x8*)&Vt[nt * 16 + c][hf * 32 + g * 8];
                oacc[nt] = __builtin_amdgcn_mfma_f32_16x16x32_bf16(af, bv, oacc[nt], 0, 0, 0);
            }
        }
    }

    #pragma unroll
    for (int j = 0; j < 4; ++j) {
        int row = mt * 16 + g * 4 + j;
        if (row < MM) {
            float invl = 1.0f / l_[j];
            #pragma unroll
            for (int nt = 0; nt < 4; ++nt)
                o[(size_t)(b * SS + rowq0 + row) * DD + h * 64 + nt * 16 + c] =
                    f2bf(oacc[nt][j] * invl);
        }
    }
}

// ---------------- SwiGLU (bf16 in/out, vectorized) ----------------
__global__ void silu_k(const unsigned short* __restrict__ u, unsigned short* __restrict__ g) {
    int idx = blockIdx.x * blockDim.x + threadIdx.x;   // ROWS*FFH/8
    int j8 = (idx & 127) * 8;
    size_t r = idx >> 7;
    bf16x8 a8 = *(const bf16x8*)&u[r * 2048 + j8];
    bf16x8 b8 = *(const bf16x8*)&u[r * 2048 + 1024 + j8];
    unsigned short o8[8];
    #pragma unroll
    for (int jj = 0; jj < 8; ++jj) {
        float a = bf2f((unsigned short)a8[jj]);
        float bb = bf2f((unsigned short)b8[jj]);
        o8[jj] = f2bf((a / (1.0f + __expf(-a))) * bb);
    }
    *(bf16x8*)&g[r * 1024 + j8] = *(const bf16x8*)o8;
}

// ---------------- extract router slots ----------------
__global__ void extract_k(const float* __restrict__ h, float* __restrict__ out) {
    int idx = blockIdx.x * blockDim.x + threadIdx.x;  // NB*LB*DD
    int d = idx % DD;
    int l = (idx / DD) % LB;
    int b = idx / (DD * LB);
    out[idx] = h[((size_t)(b * SS + l * MM + BLKN)) * DD + d];
}

extern "C" void kernel_launch(void* const* d_in, const int* in_sizes, int n_in,
                              void* d_out, int out_size, void* d_ws, size_t ws_size,
                              hipStream_t stream) {
    const float* x           = (const float*)d_in[0];
    const int*   doc         = (const int*)d_in[1];
    const float* rt          = (const float*)d_in[2];
    const float* attn_w      = (const float*)d_in[3];
    const float* attn_o_w    = (const float*)d_in[4];
    const float* ffn_up_w    = (const float*)d_in[5];
    const float* ffn_down_w  = (const float*)d_in[6];
    const float* attn_norm_w = (const float*)d_in[7];
    const float* ffn_norm_w  = (const float*)d_in[8];
    float* out = (float*)d_out;

    float* h = (float*)d_ws;                                      // ROWS*512 f32
    unsigned short* qkvb = (unsigned short*)(h + (size_t)ROWS * 512);  // ROWS*1536 bf16
    unsigned short* upb  = qkvb + (size_t)ROWS * 1536;            // ROWS*2048 bf16
    unsigned short* wt   = upb + (size_t)ROWS * 2048;             // 2*WT_LS bf16
    unsigned short* hnb  = wt + (size_t)2 * WT_LS;                // ROWS*512 bf16
    unsigned short* ob   = hnb + (size_t)ROWS * 512;              // ROWS*512 bf16
    unsigned short* gb   = hnb;                                   // ROWS*1024, aliases hnb+ob

    build_h_k<<<(NB * SS * DD) / 256, 256, 0, stream>>>(x, rt, h);

    // pre-transpose weights -> bf16 [N][K]
    for (int i = 0; i < 2; ++i) {
        unsigned short* wl = wt + (size_t)i * WT_LS;
        wtrans_k<<<dim3(1536 / 64, 512 / 64), 256, 0, stream>>>(attn_w + (size_t)i * 512 * 1536, wl, 512, 1536);
        wtrans_k<<<dim3(512 / 64, 512 / 64), 256, 0, stream>>>(attn_o_w + (size_t)i * 512 * 512, wl + 786432, 512, 512);
        wtrans_k<<<dim3(2048 / 64, 512 / 64), 256, 0, stream>>>(ffn_up_w + (size_t)i * 512 * 2048, wl + 1048576, 512, 2048);
        wtrans_k<<<dim3(512 / 64, 1024 / 64), 256, 0, stream>>>(ffn_down_w + (size_t)i * 1024 * 512, wl + 2097152, 1024, 512);
    }

    for (int i = 0; i < 2; ++i) {
        unsigned short* wl = wt + (size_t)i * WT_LS;
        const float* anw = attn_norm_w + (size_t)i * 512;
        const float* fnw = ffn_norm_w  + (size_t)i * 512;

        rmsnorm_k<<<ROWS, 256, 0, stream>>>(h, anw, hnb);
        gemm_bf16_k<0, 1><<<dim3(12, 65), 256, 0, stream>>>(hnb, wl, qkvb, 512, 1536);
        rope_bf_k<<<(NB * SS * NH * 32) / 256, 256, 0, stream>>>(qkvb);
        attn_mfma_k<<<512, 320, 0, stream>>>(qkvb, doc, ob);
        gemm_bf16_k<1, 0><<<dim3(4, 65), 256, 0, stream>>>(ob, wl + 786432, h, 512, 512);
        rmsnorm_k<<<ROWS, 256, 0, stream>>>(h, fnw, hnb);
        gemm_bf16_k<0, 1><<<dim3(16, 65), 256, 0, stream>>>(hnb, wl + 1048576, upb, 512, 2048);
        silu_k<<<(ROWS * FFH / 8) / 256, 256, 0, stream>>>(upb, gb);
        gemm_bf16_k<1, 0><<<dim3(4, 65), 256, 0, stream>>>(gb, wl + 2097152, h, 1024, 512);
    }

    extract_k<<<(NB * LB * DD) / 256, 256, 0, stream>>>(h, out);
}

// Round 5
// 260.225 us; speedup vs baseline: 16.7985x; 1.4263x over previous
//
#include <hip/hip_runtime.h>
#include <math.h>

#define NB 2          // batch
#define LB 32         // blocks
#define BLKN 64       // block size
#define MM 65         // block + router
#define SS (LB*MM)    // 2080
#define DD 512
#define NH 8
#define HD 64
#define FFH 1024
#define ROWS (NB*SS)  // 4160
#define WT_LS 2621440 // bf16 elems per layer of transposed weights

typedef __attribute__((ext_vector_type(8))) short bf16x8;
typedef __attribute__((ext_vector_type(4))) float f32x4;

__device__ __forceinline__ unsigned short f2bf(float f) {
    union { float f; unsigned u; } v; v.f = f;
    unsigned r = (v.u + 0x7FFFu + ((v.u >> 16) & 1u)) >> 16;   // RNE
    return (unsigned short)r;
}
__device__ __forceinline__ float bf2f(unsigned short u) {
    union { unsigned u; float f; } v; v.u = ((unsigned)u) << 16; return v.f;
}

__device__ __forceinline__ void gload_lds16(const unsigned short* g, unsigned short* l) {
    __builtin_amdgcn_global_load_lds((const __attribute__((address_space(1))) unsigned int*)g,
                                     (__attribute__((address_space(3))) unsigned int*)l,
                                     16, 0, 0);
}

// ---------------- build h: insert router token ----------------
__global__ void build_h_k(const float* __restrict__ x, const float* __restrict__ rt,
                          float* __restrict__ h) {
    int idx = blockIdx.x * blockDim.x + threadIdx.x;   // over NB*SS*DD
    int d = idx % DD;
    int s = (idx / DD) % SS;
    int b = idx / (DD * SS);
    int l = s / MM, j = s % MM;
    float v = (j < BLKN) ? x[((size_t)(b * LB + l) * BLKN + j) * DD + d] : rt[d];
    h[idx] = v;
}

// ---------------- rmsnorm -> bf16 ----------------
__global__ __launch_bounds__(256) void rmsnorm_k(const float* __restrict__ in,
                                                 const float* __restrict__ w,
                                                 unsigned short* __restrict__ out) {
    int row = blockIdx.x;
    const float* xr = in + (size_t)row * DD;
    unsigned short* orow = out + (size_t)row * DD;
    int t = threadIdx.x;
    float v0 = xr[t], v1 = xr[t + 256];
    float ss = v0 * v0 + v1 * v1;
    #pragma unroll
    for (int off = 32; off; off >>= 1) ss += __shfl_xor(ss, off);
    __shared__ float red[4];
    if ((t & 63) == 0) red[t >> 6] = ss;
    __syncthreads();
    float tot = red[0] + red[1] + red[2] + red[3];
    float r = rsqrtf(tot * (1.0f / 512.0f) + 1e-5f);
    orow[t] = f2bf(v0 * r * w[t]);
    orow[t + 256] = f2bf(v1 * r * w[t + 256]);
}

// ---------------- weight transpose + bf16 convert: W[K,N] f32 -> Wt[N,K] bf16 ----
__global__ __launch_bounds__(256) void wtrans_k(const float* __restrict__ W,
                                                unsigned short* __restrict__ Wt,
                                                int K, int N) {
    __shared__ unsigned short T[64][66];
    int n0 = blockIdx.x * 64, k0 = blockIdx.y * 64;
    int t = threadIdx.x;
    #pragma unroll
    for (int i = 0; i < 16; ++i) {
        int e = t + i * 256;
        int r = e >> 6, c = e & 63;
        T[r][c] = f2bf(W[(size_t)(k0 + r) * N + n0 + c]);
    }
    __syncthreads();
    #pragma unroll
    for (int i = 0; i < 16; ++i) {
        int e = t + i * 256;
        int r = e >> 6, c = e & 63;   // r = n-row, c = k-col
        Wt[(size_t)(n0 + r) * K + k0 + c] = T[c][r];
    }
}

// ---------------- bf16 MFMA GEMM: C[ROWS,N] (+)= A[ROWS,K] @ Wt[N,K]^T ----------
// 256 thr = 4 waves; WG tile 64(M) x 128(N); BK=64; XOR-swizzled LDS.
// OBF=1: write bf16 (no ADD). ROPE=1: apply rotary to q/k sections in epilogue.
template <int ADD, int OBF, int ROPE>
__global__ __launch_bounds__(256) void gemm_bf16_k(const unsigned short* __restrict__ A,
                                                   const unsigned short* __restrict__ Wt,
                                                   void* __restrict__ Cp,
                                                   int K, int N) {
    __shared__ unsigned short As[64 * 64];    // 8 KB, swizzled rows of 128B
    __shared__ unsigned short Bs[128 * 64];   // 16 KB
    int t = threadIdx.x;
    int lane = t & 63, wv = t >> 6;
    int wm = wv >> 1, wn = wv & 1;
    int rowBase = blockIdx.y * 64, colBase = blockIdx.x * 128;
    int c = lane & 15, g = lane >> 4;
    int sw = (c & 7) << 4;

    f32x4 acc[2][4];
    #pragma unroll
    for (int mt = 0; mt < 2; ++mt)
        #pragma unroll
        for (int nt = 0; nt < 4; ++nt) { f32x4 z = {0, 0, 0, 0}; acc[mt][nt] = z; }

    for (int k0 = 0; k0 < K; k0 += 64) {
        __syncthreads();
        #pragma unroll
        for (int i = 0; i < 2; ++i) {
            int e0 = (i * 4 + wv) * 64;
            int e = e0 + lane;
            int row = e >> 3;
            int kb = ((e & 7) << 4) ^ ((row & 7) << 4);
            gload_lds16(A + (size_t)(rowBase + row) * K + k0 + (kb >> 1), &As[e0 * 8]);
        }
        #pragma unroll
        for (int i = 0; i < 4; ++i) {
            int e0 = (i * 4 + wv) * 64;
            int e = e0 + lane;
            int row = e >> 3;
            int kb = ((e & 7) << 4) ^ ((row & 7) << 4);
            gload_lds16(Wt + (size_t)(colBase + row) * K + k0 + (kb >> 1), &Bs[e0 * 8]);
        }
        __syncthreads();   // drains vmcnt(0) too

        bf16x8 af[2][2], bfr[4][2];
        #pragma unroll
        for (int mt = 0; mt < 2; ++mt)
            #pragma unroll
            for (int hf = 0; hf < 2; ++hf)
                af[mt][hf] = *(const bf16x8*)
                    &As[((wm * 32 + mt * 16 + c) * 128 + ((hf * 64 + g * 16) ^ sw)) >> 1];
        #pragma unroll
        for (int nt = 0; nt < 4; ++nt)
            #pragma unroll
            for (int hf = 0; hf < 2; ++hf)
                bfr[nt][hf] = *(const bf16x8*)
                    &Bs[((wn * 64 + nt * 16 + c) * 128 + ((hf * 64 + g * 16) ^ sw)) >> 1];
        #pragma unroll
        for (int mt = 0; mt < 2; ++mt)
            #pragma unroll
            for (int nt = 0; nt < 4; ++nt) {
                acc[mt][nt] = __builtin_amdgcn_mfma_f32_16x16x32_bf16(af[mt][0], bfr[nt][0], acc[mt][nt], 0, 0, 0);
                acc[mt][nt] = __builtin_amdgcn_mfma_f32_16x16x32_bf16(af[mt][1], bfr[nt][1], acc[mt][nt], 0, 0, 0);
            }
    }

    // fused rotary for q/k sections (col-pairs j, j+32 live in acc[mt][p], acc[mt][p+2])
    if (ROPE) {
        int sec = (colBase + wn * 64) >> 9;   // 0:q 1:k 2:v
        if (sec < 2) {
            #pragma unroll
            for (int mt = 0; mt < 2; ++mt)
                #pragma unroll
                for (int j = 0; j < 4; ++j) {
                    int row = rowBase + wm * 32 + mt * 16 + g * 4 + j;
                    int spos = row % SS;
                    #pragma unroll
                    for (int p = 0; p < 2; ++p) {
                        float jj = (float)(c + p * 16);
                        float inv = exp2f(jj * -0.41524101186092030f); // (1e-4)^(j/32)
                        float fr = (float)spos * inv;
                        float sn, cs; __sincosf(fr, &sn, &cs);
                        float a = acc[mt][p][j], bb = acc[mt][p + 2][j];
                        acc[mt][p][j] = a * cs + bb * sn;
                        acc[mt][p + 2][j] = -a * sn + bb * cs;
                    }
                }
        }
    }

    #pragma unroll
    for (int mt = 0; mt < 2; ++mt)
        #pragma unroll
        for (int j = 0; j < 4; ++j) {
            int row = rowBase + wm * 32 + mt * 16 + g * 4 + j;
            size_t off = (size_t)row * N + colBase + wn * 64 + c;
            if (OBF) {
                unsigned short* cr = (unsigned short*)Cp + off;
                #pragma unroll
                for (int nt = 0; nt < 4; ++nt) cr[nt * 16] = f2bf(acc[mt][nt][j]);
            } else {
                float* cr = (float*)Cp + off;
                #pragma unroll
                for (int nt = 0; nt < 4; ++nt) {
                    if (ADD) cr[nt * 16] += acc[mt][nt][j];
                    else     cr[nt * 16] = acc[mt][nt][j];
                }
            }
        }
}

// ---------------- flash attention, bf16 MFMA, 5 waves, doc-skip + pipelined ----
#define QR 80

__global__ __launch_bounds__(320) void attn_mfma_k(const unsigned short* __restrict__ qkv,
                                                   const int* __restrict__ doc,
                                                   unsigned short* __restrict__ o) {
    __shared__ unsigned short Qs[QR * 64];       // XOR-swizzled, 128B rows
    __shared__ unsigned short Ks[2][64 * 64];    // double-buffered, swizzled
    __shared__ unsigned short Vt[2][64][72];     // transposed [d][key], padded
    __shared__ unsigned short Ps[5][16][72];     // wave-private P tiles
    __shared__ int docq[QR];
    __shared__ int dock[2][64];

    int idx = blockIdx.x;
    int l = 31 - (idx >> 4);
    int b = (idx >> 3) & 1;
    int h = idx & 7;
    int t = threadIdx.x;
    int lane = t & 63;
    int wv = t >> 6;

    const unsigned short* qb = qkv + (size_t)b * SS * 1536;
    int rowq0 = l * MM;
    int kmax = (l + 1) * MM;

    // stage Q swizzled: 640 x 16B over 320 threads
    #pragma unroll
    for (int it = 0; it < 2; ++it) {
        int ebase = it * 320 + wv * 64;
        int e = ebase + lane;
        int row = e >> 3;
        int kb = ((e & 7) << 4) ^ ((row & 7) << 4);
        int gr = rowq0 + row; if (gr > SS - 1) gr = SS - 1;
        gload_lds16(qb + (size_t)gr * 1536 + h * 64 + (kb >> 1), &Qs[ebase * 8]);
    }
    if (t < QR) docq[t] = (t < MM) ? doc[b * SS + rowq0 + t] : -999999;

    // doc-range skip: first key tile containing this block's first doc
    int d0 = doc[b * SS + rowq0];
    int lo = 0, hi = rowq0;
    while (lo < hi) {
        int mid = (lo + hi) >> 1;
        if (doc[b * SS + mid] < d0) lo = mid + 1; else hi = mid;
    }
    int kts = lo >> 6;
    int nkt = (kmax + 63) >> 6;

    const int mt = wv;
    const int g = lane >> 4;
    const int c = lane & 15;
    const int sw = (c & 7) << 4;

    // ---- staging helpers ----
    auto stageK = [&](int kbase, int buf) {
        int ebase = wv * 64;
        int e = ebase + lane;
        int row = e >> 3;
        int kb = ((e & 7) << 4) ^ ((row & 7) << 4);
        int kg = kbase + row; if (kg > kmax - 1) kg = kmax - 1;
        gload_lds16(qb + (size_t)kg * 1536 + 512 + h * 64 + (kb >> 1), &Ks[buf][ebase * 8]);
        if (wv < 3) {
            int eb2 = 320 + wv * 64;
            int e2 = eb2 + lane;
            int row2 = e2 >> 3;
            int kb2 = ((e2 & 7) << 4) ^ ((row2 & 7) << 4);
            int kg2 = kbase + row2; if (kg2 > kmax - 1) kg2 = kmax - 1;
            gload_lds16(qb + (size_t)kg2 * 1536 + 512 + h * 64 + (kb2 >> 1), &Ks[buf][eb2 * 8]);
        }
    };
    bf16x8 vr0, vr1; int dnx = 0;
    auto loadV = [&](int kbase) {
        int key = t & 63;
        int de = (t >> 6) * 8;
        int kg = kbase + key; if (kg > kmax - 1) kg = kmax - 1;
        vr0 = *(const bf16x8*)(qb + (size_t)kg * 1536 + 1024 + h * 64 + de);
        if (t < 192) {
            int e2 = 320 + t;
            int key2 = e2 & 63;
            int de2 = (e2 >> 6) * 8;
            int kg2 = kbase + key2; if (kg2 > kmax - 1) kg2 = kmax - 1;
            vr1 = *(const bf16x8*)(qb + (size_t)kg2 * 1536 + 1024 + h * 64 + de2);
        }
        if (t < 64) dnx = (kbase + t < kmax) ? doc[b * SS + kbase + t] : -1000000;
    };
    auto writeV = [&](int buf) {
        int key = t & 63;
        int de = (t >> 6) * 8;
        #pragma unroll
        for (int jj = 0; jj < 8; ++jj) Vt[buf][de + jj][key] = ((unsigned short*)&vr0)[jj];
        if (t < 192) {
            int e2 = 320 + t;
            int key2 = e2 & 63;
            int de2 = (e2 >> 6) * 8;
            #pragma unroll
            for (int jj = 0; jj < 8; ++jj) Vt[buf][de2 + jj][key2] = ((unsigned short*)&vr1)[jj];
        }
        if (t < 64) dock[buf][t] = dnx;
    };

    // prologue: stage first tile into buf 0
    stageK(kts << 6, 0);
    loadV(kts << 6);
    writeV(0);
    __syncthreads();   // Qs, Ks[0], Vt[0], docq, dock[0] all ready

    // hoist Q fragments + query docs into registers (constant across tiles)
    bf16x8 aq[2];
    #pragma unroll
    for (int hf = 0; hf < 2; ++hf)
        aq[hf] = *(const bf16x8*)&Qs[((mt * 16 + c) * 128 + ((hf * 64 + g * 16) ^ sw)) >> 1];
    int dq[4];
    #pragma unroll
    for (int j = 0; j < 4; ++j) dq[j] = docq[mt * 16 + g * 4 + j];

    f32x4 oacc[4];
    float m_[4], l_[4];
    #pragma unroll
    for (int nt = 0; nt < 4; ++nt) { f32x4 z = {0,0,0,0}; oacc[nt] = z; }
    #pragma unroll
    for (int j = 0; j < 4; ++j) { m_[j] = -1e30f; l_[j] = 0.0f; }

    for (int kt = kts; kt < nkt; ++kt) {
        int cur = (kt - kts) & 1;
        bool more = (kt + 1 < nkt);
        if (more) {                      // issue next-tile loads (fly during compute)
            stageK((kt + 1) << 6, cur ^ 1);
            loadV((kt + 1) << 6);
        }

        // ---- S = Q K^T ----
        f32x4 s[4];
        #pragma unroll
        for (int sub = 0; sub < 4; ++sub) {
            f32x4 acc = {0, 0, 0, 0};
            #pragma unroll
            for (int hf = 0; hf < 2; ++hf) {
                bf16x8 bk = *(const bf16x8*)
                    &Ks[cur][((sub * 16 + c) * 128 + ((hf * 64 + g * 16) ^ sw)) >> 1];
                acc = __builtin_amdgcn_mfma_f32_16x16x32_bf16(aq[hf], bk, acc, 0, 0, 0);
            }
            s[sub] = acc;
        }
        // ---- mask + scale ----
        #pragma unroll
        for (int sub = 0; sub < 4; ++sub) {
            int dk = dock[cur][sub * 16 + c];
            #pragma unroll
            for (int j = 0; j < 4; ++j)
                s[sub][j] = (dq[j] == dk) ? s[sub][j] * 0.125f : -1e30f;
        }
        // ---- tile row-max ----
        float mx[4];
        #pragma unroll
        for (int j = 0; j < 4; ++j)
            mx[j] = fmaxf(fmaxf(s[0][j], s[1][j]), fmaxf(s[2][j], s[3][j]));
        #pragma unroll
        for (int off = 1; off < 16; off <<= 1)
            #pragma unroll
            for (int j = 0; j < 4; ++j) mx[j] = fmaxf(mx[j], __shfl_xor(mx[j], off));
        // ---- online softmax update ----
        float mn[4], sc[4], rs[4];
        #pragma unroll
        for (int j = 0; j < 4; ++j) {
            mn[j] = fmaxf(m_[j], mx[j]);
            sc[j] = __expf(m_[j] - mn[j]);
            m_[j] = mn[j];
            rs[j] = 0.0f;
        }
        #pragma unroll
        for (int sub = 0; sub < 4; ++sub)
            #pragma unroll
            for (int j = 0; j < 4; ++j) {
                float p = __expf(s[sub][j] - mn[j]);
                rs[j] += p;
                Ps[wv][g * 4 + j][sub * 16 + c] = f2bf(p);
            }
        #pragma unroll
        for (int off = 1; off < 16; off <<= 1)
            #pragma unroll
            for (int j = 0; j < 4; ++j) rs[j] += __shfl_xor(rs[j], off);
        #pragma unroll
        for (int j = 0; j < 4; ++j) l_[j] = l_[j] * sc[j] + rs[j];
        #pragma unroll
        for (int nt = 0; nt < 4; ++nt)
            #pragma unroll
            for (int j = 0; j < 4; ++j) oacc[nt][j] *= sc[j];
        // ---- O += P V ----
        #pragma unroll
        for (int hf = 0; hf < 2; ++hf) {
            bf16x8 af = *(const bf16x8*)&Ps[wv][c][hf * 32 + g * 8];
            #pragma unroll
            for (int nt = 0; nt < 4; ++nt) {
                bf16x8 bv = *(const bf16x8*)&Vt[cur][nt * 16 + c][hf * 32 + g * 8];
                oacc[nt] = __builtin_amdgcn_mfma_f32_16x16x32_bf16(af, bv, oacc[nt], 0, 0, 0);
            }
        }

        if (more) writeV(cur ^ 1);   // V regs landed during compute
        __syncthreads();
    }

    #pragma unroll
    for (int j = 0; j < 4; ++j) {
        int row = mt * 16 + g * 4 + j;
        if (row < MM) {
            float invl = 1.0f / l_[j];
            #pragma unroll
            for (int nt = 0; nt < 4; ++nt)
                o[(size_t)(b * SS + rowq0 + row) * DD + h * 64 + nt * 16 + c] =
                    f2bf(oacc[nt][j] * invl);
        }
    }
}

// ---------------- SwiGLU (bf16 in/out, vectorized) ----------------
__global__ void silu_k(const unsigned short* __restrict__ u, unsigned short* __restrict__ g) {
    int idx = blockIdx.x * blockDim.x + threadIdx.x;   // ROWS*FFH/8
    int j8 = (idx & 127) * 8;
    size_t r = idx >> 7;
    bf16x8 a8 = *(const bf16x8*)&u[r * 2048 + j8];
    bf16x8 b8 = *(const bf16x8*)&u[r * 2048 + 1024 + j8];
    unsigned short o8[8];
    #pragma unroll
    for (int jj = 0; jj < 8; ++jj) {
        float a = bf2f((unsigned short)a8[jj]);
        float bb = bf2f((unsigned short)b8[jj]);
        o8[jj] = f2bf((a / (1.0f + __expf(-a))) * bb);
    }
    *(bf16x8*)&g[r * 1024 + j8] = *(const bf16x8*)o8;
}

// ---------------- extract router slots ----------------
__global__ void extract_k(const float* __restrict__ h, float* __restrict__ out) {
    int idx = blockIdx.x * blockDim.x + threadIdx.x;  // NB*LB*DD
    int d = idx % DD;
    int l = (idx / DD) % LB;
    int b = idx / (DD * LB);
    out[idx] = h[((size_t)(b * SS + l * MM + BLKN)) * DD + d];
}

extern "C" void kernel_launch(void* const* d_in, const int* in_sizes, int n_in,
                              void* d_out, int out_size, void* d_ws, size_t ws_size,
                              hipStream_t stream) {
    const float* x           = (const float*)d_in[0];
    const int*   doc         = (const int*)d_in[1];
    const float* rt          = (const float*)d_in[2];
    const float* attn_w      = (const float*)d_in[3];
    const float* attn_o_w    = (const float*)d_in[4];
    const float* ffn_up_w    = (const float*)d_in[5];
    const float* ffn_down_w  = (const float*)d_in[6];
    const float* attn_norm_w = (const float*)d_in[7];
    const float* ffn_norm_w  = (const float*)d_in[8];
    float* out = (float*)d_out;

    float* h = (float*)d_ws;                                      // ROWS*512 f32
    unsigned short* qkvb = (unsigned short*)(h + (size_t)ROWS * 512);  // ROWS*1536 bf16
    unsigned short* upb  = qkvb + (size_t)ROWS * 1536;            // ROWS*2048 bf16
    unsigned short* wt   = upb + (size_t)ROWS * 2048;             // 2*WT_LS bf16
    unsigned short* hnb  = wt + (size_t)2 * WT_LS;                // ROWS*512 bf16
    unsigned short* ob   = hnb + (size_t)ROWS * 512;              // ROWS*512 bf16
    unsigned short* gb   = hnb;                                   // ROWS*1024, aliases hnb+ob

    build_h_k<<<(NB * SS * DD) / 256, 256, 0, stream>>>(x, rt, h);

    // pre-transpose weights -> bf16 [N][K]
    for (int i = 0; i < 2; ++i) {
        unsigned short* wl = wt + (size_t)i * WT_LS;
        wtrans_k<<<dim3(1536 / 64, 512 / 64), 256, 0, stream>>>(attn_w + (size_t)i * 512 * 1536, wl, 512, 1536);
        wtrans_k<<<dim3(512 / 64, 512 / 64), 256, 0, stream>>>(attn_o_w + (size_t)i * 512 * 512, wl + 786432, 512, 512);
        wtrans_k<<<dim3(2048 / 64, 512 / 64), 256, 0, stream>>>(ffn_up_w + (size_t)i * 512 * 2048, wl + 1048576, 512, 2048);
        wtrans_k<<<dim3(512 / 64, 1024 / 64), 256, 0, stream>>>(ffn_down_w + (size_t)i * 1024 * 512, wl + 2097152, 1024, 512);
    }

    for (int i = 0; i < 2; ++i) {
        unsigned short* wl = wt + (size_t)i * WT_LS;
        const float* anw = attn_norm_w + (size_t)i * 512;
        const float* fnw = ffn_norm_w  + (size_t)i * 512;

        rmsnorm_k<<<ROWS, 256, 0, stream>>>(h, anw, hnb);
        gemm_bf16_k<0, 1, 1><<<dim3(12, 65), 256, 0, stream>>>(hnb, wl, qkvb, 512, 1536);
        attn_mfma_k<<<512, 320, 0, stream>>>(qkvb, doc, ob);
        gemm_bf16_k<1, 0, 0><<<dim3(4, 65), 256, 0, stream>>>(ob, wl + 786432, h, 512, 512);
        rmsnorm_k<<<ROWS, 256, 0, stream>>>(h, fnw, hnb);
        gemm_bf16_k<0, 1, 0><<<dim3(16, 65), 256, 0, stream>>>(hnb, wl + 1048576, upb, 512, 2048);
        silu_k<<<(ROWS * FFH / 8) / 256, 256, 0, stream>>>(upb, gb);
        gemm_bf16_k<1, 0, 0><<<dim3(4, 65), 256, 0, stream>>>(gb, wl + 2097152, h, 1024, 512);
    }

    extract_k<<<(NB * LB * DD) / 256, 256, 0, stream>>>(h, out);
}

// Round 6
// 226.189 us; speedup vs baseline: 19.3262x; 1.1505x over previous
//
#include <hip/hip_runtime.h>
#include <math.h>

#define NB 2          // batch
#define LB 32         // blocks
#define BLKN 64       // block size
#define MM 65         // block + router
#define SS (LB*MM)    // 2080
#define DD 512
#define NH 8
#define HD 64
#define FFH 1024
#define ROWS (NB*SS)  // 4160
#define WT_LS 2621440 // bf16 elems per layer of transposed weights

typedef __attribute__((ext_vector_type(8))) short bf16x8;
typedef __attribute__((ext_vector_type(4))) float f32x4;

__device__ __forceinline__ unsigned short f2bf(float f) {
    union { float f; unsigned u; } v; v.f = f;
    unsigned r = (v.u + 0x7FFFu + ((v.u >> 16) & 1u)) >> 16;   // RNE
    return (unsigned short)r;
}
__device__ __forceinline__ float bf2f(unsigned short u) {
    union { unsigned u; float f; } v; v.u = ((unsigned)u) << 16; return v.f;
}

__device__ __forceinline__ void gload_lds16(const unsigned short* g, unsigned short* l) {
    __builtin_amdgcn_global_load_lds((const __attribute__((address_space(1))) unsigned int*)g,
                                     (__attribute__((address_space(3))) unsigned int*)l,
                                     16, 0, 0);
}

// ---------------- rmsnorm, wave-per-row (4 rows/WG). FIRST: build h from x/rt ---
template <int FIRST>
__global__ __launch_bounds__(256) void rms4_k(const float* __restrict__ hsrc,
                                              const float* __restrict__ x,
                                              const float* __restrict__ rt,
                                              const float* __restrict__ w,
                                              float* __restrict__ hout,
                                              unsigned short* __restrict__ out) {
    int row = blockIdx.x * 4 + (threadIdx.x >> 6);
    int lane = threadIdx.x & 63;
    const float* sp;
    if (FIRST) {
        int s = row % SS, b = row / SS;
        int l = s / MM, j = s % MM;
        sp = (j < BLKN) ? x + ((size_t)(b * LB + l) * BLKN + j) * DD : rt;
    } else {
        sp = hsrc + (size_t)row * DD;
    }
    float4 a = *(const float4*)(sp + lane * 8);
    float4 bq = *(const float4*)(sp + lane * 8 + 4);
    float ss = a.x * a.x + a.y * a.y + a.z * a.z + a.w * a.w
             + bq.x * bq.x + bq.y * bq.y + bq.z * bq.z + bq.w * bq.w;
    #pragma unroll
    for (int off = 32; off; off >>= 1) ss += __shfl_xor(ss, off);
    float r = rsqrtf(ss * (1.0f / 512.0f) + 1e-5f);
    float4 w0 = *(const float4*)(w + lane * 8);
    float4 w1 = *(const float4*)(w + lane * 8 + 4);
    unsigned short o8[8] = {f2bf(a.x * r * w0.x), f2bf(a.y * r * w0.y),
                            f2bf(a.z * r * w0.z), f2bf(a.w * r * w0.w),
                            f2bf(bq.x * r * w1.x), f2bf(bq.y * r * w1.y),
                            f2bf(bq.z * r * w1.z), f2bf(bq.w * r * w1.w)};
    *(bf16x8*)(out + (size_t)row * DD + lane * 8) = *(const bf16x8*)o8;
    if (FIRST) {
        *(float4*)(hout + (size_t)row * DD + lane * 8) = a;
        *(float4*)(hout + (size_t)row * DD + lane * 8 + 4) = bq;
    }
}

// ---------------- all weight transposes in ONE kernel ----------------
// tiles: attn_w 192, o_w 64, up_w 256 (permuted cols), down_w 128  => 640/layer
__global__ __launch_bounds__(256) void wtrans_all_k(const float* __restrict__ attn_w,
                                                    const float* __restrict__ attn_o_w,
                                                    const float* __restrict__ up_w,
                                                    const float* __restrict__ down_w,
                                                    unsigned short* __restrict__ wt) {
    __shared__ unsigned short T[64][66];
    int wg = blockIdx.x;
    int layer = wg >= 640;
    int r = wg - layer * 640;
    const float* W; int K, N; size_t dstOff; int perm = 0;
    if (r < 192)      { W = attn_w   + (size_t)layer * 512 * 1536; K = 512;  N = 1536; dstOff = 0; }
    else if (r < 256) { W = attn_o_w + (size_t)layer * 512 * 512;  K = 512;  N = 512;  dstOff = 786432;  r -= 192; }
    else if (r < 512) { W = up_w     + (size_t)layer * 512 * 2048; K = 512;  N = 2048; dstOff = 1048576; perm = 1; r -= 256; }
    else              { W = down_w   + (size_t)layer * 1024 * 512; K = 1024; N = 512;  dstOff = 2097152; r -= 512; }
    unsigned short* dst = wt + (size_t)layer * WT_LS + dstOff;
    int ntn = N >> 6;
    int n0 = (r % ntn) * 64, k0 = (r / ntn) * 64;
    int t = threadIdx.x;
    #pragma unroll
    for (int i = 0; i < 16; ++i) {
        int e = t + i * 256;
        int rr = e >> 6, cc = e & 63;
        T[rr][cc] = f2bf(W[(size_t)(k0 + rr) * N + n0 + cc]);
    }
    __syncthreads();
    #pragma unroll
    for (int i = 0; i < 16; ++i) {
        int e = t + i * 256;
        int rr = e >> 6, cc = e & 63;   // rr = n-row, cc = k-col
        int n = n0 + rr;
        int nr = n;
        if (perm) {
            int p = n & 1023;
            nr = ((p >> 4) << 5) | ((n >> 10) << 4) | (p & 15);
        }
        dst[(size_t)nr * K + k0 + cc] = T[cc][rr];
    }
}

// ---------------- bf16 MFMA GEMM: C[ROWS,N] (+)= A[ROWS,K] @ Wt[N,K]^T ----------
// 256 thr = 4 waves; WG tile 64(M) x 128(N); BK=64; XOR-swizzled LDS.
// OBF: write bf16. ROPE: rotary on q/k sections. SILU: fused SwiGLU -> gb[.,1024]
template <int ADD, int OBF, int ROPE, int SILU>
__global__ __launch_bounds__(256) void gemm_bf16_k(const unsigned short* __restrict__ A,
                                                   const unsigned short* __restrict__ Wt,
                                                   void* __restrict__ Cp,
                                                   int K, int N) {
    __shared__ unsigned short As[64 * 64];    // 8 KB, swizzled rows of 128B
    __shared__ unsigned short Bs[128 * 64];   // 16 KB
    int t = threadIdx.x;
    int lane = t & 63, wv = t >> 6;
    int wm = wv >> 1, wn = wv & 1;
    int rowBase = blockIdx.y * 64, colBase = blockIdx.x * 128;
    int c = lane & 15, g = lane >> 4;
    int sw = (c & 7) << 4;

    f32x4 acc[2][4];
    #pragma unroll
    for (int mt = 0; mt < 2; ++mt)
        #pragma unroll
        for (int nt = 0; nt < 4; ++nt) { f32x4 z = {0, 0, 0, 0}; acc[mt][nt] = z; }

    for (int k0 = 0; k0 < K; k0 += 64) {
        __syncthreads();
        #pragma unroll
        for (int i = 0; i < 2; ++i) {
            int e0 = (i * 4 + wv) * 64;
            int e = e0 + lane;
            int row = e >> 3;
            int kb = ((e & 7) << 4) ^ ((row & 7) << 4);
            gload_lds16(A + (size_t)(rowBase + row) * K + k0 + (kb >> 1), &As[e0 * 8]);
        }
        #pragma unroll
        for (int i = 0; i < 4; ++i) {
            int e0 = (i * 4 + wv) * 64;
            int e = e0 + lane;
            int row = e >> 3;
            int kb = ((e & 7) << 4) ^ ((row & 7) << 4);
            gload_lds16(Wt + (size_t)(colBase + row) * K + k0 + (kb >> 1), &Bs[e0 * 8]);
        }
        __syncthreads();   // drains vmcnt(0) too

        bf16x8 af[2][2], bfr[4][2];
        #pragma unroll
        for (int mt = 0; mt < 2; ++mt)
            #pragma unroll
            for (int hf = 0; hf < 2; ++hf)
                af[mt][hf] = *(const bf16x8*)
                    &As[((wm * 32 + mt * 16 + c) * 128 + ((hf * 64 + g * 16) ^ sw)) >> 1];
        #pragma unroll
        for (int nt = 0; nt < 4; ++nt)
            #pragma unroll
            for (int hf = 0; hf < 2; ++hf)
                bfr[nt][hf] = *(const bf16x8*)
                    &Bs[((wn * 64 + nt * 16 + c) * 128 + ((hf * 64 + g * 16) ^ sw)) >> 1];
        __builtin_amdgcn_s_setprio(1);
        #pragma unroll
        for (int mt = 0; mt < 2; ++mt)
            #pragma unroll
            for (int nt = 0; nt < 4; ++nt) {
                acc[mt][nt] = __builtin_amdgcn_mfma_f32_16x16x32_bf16(af[mt][0], bfr[nt][0], acc[mt][nt], 0, 0, 0);
                acc[mt][nt] = __builtin_amdgcn_mfma_f32_16x16x32_bf16(af[mt][1], bfr[nt][1], acc[mt][nt], 0, 0, 0);
            }
        __builtin_amdgcn_s_setprio(0);
    }

    // fused rotary for q/k sections (col-pairs j, j+32 live in acc[mt][p], acc[mt][p+2])
    if (ROPE) {
        int sec = (colBase + wn * 64) >> 9;   // 0:q 1:k 2:v
        if (sec < 2) {
            #pragma unroll
            for (int mt = 0; mt < 2; ++mt)
                #pragma unroll
                for (int j = 0; j < 4; ++j) {
                    int row = rowBase + wm * 32 + mt * 16 + g * 4 + j;
                    int spos = row % SS;
                    #pragma unroll
                    for (int p = 0; p < 2; ++p) {
                        float jj = (float)(c + p * 16);
                        float inv = exp2f(jj * -0.41524101186092030f); // (1e-4)^(j/32)
                        float fr = (float)spos * inv;
                        float sn, cs; __sincosf(fr, &sn, &cs);
                        float a = acc[mt][p][j], bb = acc[mt][p + 2][j];
                        acc[mt][p][j] = a * cs + bb * sn;
                        acc[mt][p + 2][j] = -a * sn + bb * cs;
                    }
                }
        }
    }

    #pragma unroll
    for (int mt = 0; mt < 2; ++mt)
        #pragma unroll
        for (int j = 0; j < 4; ++j) {
            int row = rowBase + wm * 32 + mt * 16 + g * 4 + j;
            if (SILU) {
                // acc[2p] = u1, acc[2p+1] = u2 for the same output col p-group
                unsigned short* gr = (unsigned short*)Cp + (size_t)row * 1024;
                #pragma unroll
                for (int ntp = 0; ntp < 2; ++ntp) {
                    int npr = colBase + wn * 64 + ntp * 32;      // bit4 == 0
                    int p = ((npr >> 5) << 4) + c;
                    float u1 = acc[mt][2 * ntp][j];
                    float u2 = acc[mt][2 * ntp + 1][j];
                    gr[p] = f2bf((u1 / (1.0f + __expf(-u1))) * u2);
                }
            } else {
                size_t off = (size_t)row * N + colBase + wn * 64 + c;
                if (OBF) {
                    unsigned short* cr = (unsigned short*)Cp + off;
                    #pragma unroll
                    for (int nt = 0; nt < 4; ++nt) cr[nt * 16] = f2bf(acc[mt][nt][j]);
                } else {
                    float* cr = (float*)Cp + off;
                    #pragma unroll
                    for (int nt = 0; nt < 4; ++nt) {
                        if (ADD) cr[nt * 16] += acc[mt][nt][j];
                        else     cr[nt * 16] = acc[mt][nt][j];
                    }
                }
            }
        }
}

// ---------------- flash attention, bf16 MFMA, 5 waves, doc-skip + pipelined ----
#define QR 80

__global__ __launch_bounds__(320) void attn_mfma_k(const unsigned short* __restrict__ qkv,
                                                   const int* __restrict__ doc,
                                                   unsigned short* __restrict__ o) {
    __shared__ unsigned short Qs[QR * 64];       // XOR-swizzled, 128B rows
    __shared__ unsigned short Ks[2][64 * 64];    // double-buffered, swizzled
    __shared__ unsigned short Vt[2][64][72];     // transposed [d][key], padded
    __shared__ unsigned short Ps[5][16][72];     // wave-private P tiles
    __shared__ int docq[QR];
    __shared__ int dock[2][64];

    int idx = blockIdx.x;
    int l = 31 - (idx >> 4);
    int b = (idx >> 3) & 1;
    int h = idx & 7;
    int t = threadIdx.x;
    int lane = t & 63;
    int wv = t >> 6;

    const unsigned short* qb = qkv + (size_t)b * SS * 1536;
    int rowq0 = l * MM;
    int kmax = (l + 1) * MM;

    // stage Q swizzled: 640 x 16B over 320 threads
    #pragma unroll
    for (int it = 0; it < 2; ++it) {
        int ebase = it * 320 + wv * 64;
        int e = ebase + lane;
        int row = e >> 3;
        int kb = ((e & 7) << 4) ^ ((row & 7) << 4);
        int gr = rowq0 + row; if (gr > SS - 1) gr = SS - 1;
        gload_lds16(qb + (size_t)gr * 1536 + h * 64 + (kb >> 1), &Qs[ebase * 8]);
    }
    if (t < QR) docq[t] = (t < MM) ? doc[b * SS + rowq0 + t] : -999999;

    // doc-range skip: first key tile containing this block's first doc
    int d0 = doc[b * SS + rowq0];
    int lo = 0, hi = rowq0;
    while (lo < hi) {
        int mid = (lo + hi) >> 1;
        if (doc[b * SS + mid] < d0) lo = mid + 1; else hi = mid;
    }
    int kts = lo >> 6;
    int nkt = (kmax + 63) >> 6;

    const int mt = wv;
    const int g = lane >> 4;
    const int c = lane & 15;
    const int sw = (c & 7) << 4;

    // ---- staging helpers ----
    auto stageK = [&](int kbase, int buf) {
        int ebase = wv * 64;
        int e = ebase + lane;
        int row = e >> 3;
        int kb = ((e & 7) << 4) ^ ((row & 7) << 4);
        int kg = kbase + row; if (kg > kmax - 1) kg = kmax - 1;
        gload_lds16(qb + (size_t)kg * 1536 + 512 + h * 64 + (kb >> 1), &Ks[buf][ebase * 8]);
        if (wv < 3) {
            int eb2 = 320 + wv * 64;
            int e2 = eb2 + lane;
            int row2 = e2 >> 3;
            int kb2 = ((e2 & 7) << 4) ^ ((row2 & 7) << 4);
            int kg2 = kbase + row2; if (kg2 > kmax - 1) kg2 = kmax - 1;
            gload_lds16(qb + (size_t)kg2 * 1536 + 512 + h * 64 + (kb2 >> 1), &Ks[buf][eb2 * 8]);
        }
    };
    bf16x8 vr0, vr1; int dnx = 0;
    auto loadV = [&](int kbase) {
        int key = t & 63;
        int de = (t >> 6) * 8;
        int kg = kbase + key; if (kg > kmax - 1) kg = kmax - 1;
        vr0 = *(const bf16x8*)(qb + (size_t)kg * 1536 + 1024 + h * 64 + de);
        if (t < 192) {
            int e2 = 320 + t;
            int key2 = e2 & 63;
            int de2 = (e2 >> 6) * 8;
            int kg2 = kbase + key2; if (kg2 > kmax - 1) kg2 = kmax - 1;
            vr1 = *(const bf16x8*)(qb + (size_t)kg2 * 1536 + 1024 + h * 64 + de2);
        }
        if (t < 64) dnx = (kbase + t < kmax) ? doc[b * SS + kbase + t] : -1000000;
    };
    auto writeV = [&](int buf) {
        int key = t & 63;
        int de = (t >> 6) * 8;
        #pragma unroll
        for (int jj = 0; jj < 8; ++jj) Vt[buf][de + jj][key] = ((unsigned short*)&vr0)[jj];
        if (t < 192) {
            int e2 = 320 + t;
            int key2 = e2 & 63;
            int de2 = (e2 >> 6) * 8;
            #pragma unroll
            for (int jj = 0; jj < 8; ++jj) Vt[buf][de2 + jj][key2] = ((unsigned short*)&vr1)[jj];
        }
        if (t < 64) dock[buf][t] = dnx;
    };

    // prologue: stage first tile into buf 0
    stageK(kts << 6, 0);
    loadV(kts << 6);
    writeV(0);
    __syncthreads();   // Qs, Ks[0], Vt[0], docq, dock[0] all ready

    // hoist Q fragments + query docs into registers (constant across tiles)
    bf16x8 aq[2];
    #pragma unroll
    for (int hf = 0; hf < 2; ++hf)
        aq[hf] = *(const bf16x8*)&Qs[((mt * 16 + c) * 128 + ((hf * 64 + g * 16) ^ sw)) >> 1];
    int dq[4];
    #pragma unroll
    for (int j = 0; j < 4; ++j) dq[j] = docq[mt * 16 + g * 4 + j];

    f32x4 oacc[4];
    float m_[4], l_[4];
    #pragma unroll
    for (int nt = 0; nt < 4; ++nt) { f32x4 z = {0,0,0,0}; oacc[nt] = z; }
    #pragma unroll
    for (int j = 0; j < 4; ++j) { m_[j] = -1e30f; l_[j] = 0.0f; }

    for (int kt = kts; kt < nkt; ++kt) {
        int cur = (kt - kts) & 1;
        bool more = (kt + 1 < nkt);
        if (more) {                      // issue next-tile loads (fly during compute)
            stageK((kt + 1) << 6, cur ^ 1);
            loadV((kt + 1) << 6);
        }

        // ---- S = Q K^T ----
        f32x4 s[4];
        __builtin_amdgcn_s_setprio(1);
        #pragma unroll
        for (int sub = 0; sub < 4; ++sub) {
            f32x4 acc = {0, 0, 0, 0};
            #pragma unroll
            for (int hf = 0; hf < 2; ++hf) {
                bf16x8 bk = *(const bf16x8*)
                    &Ks[cur][((sub * 16 + c) * 128 + ((hf * 64 + g * 16) ^ sw)) >> 1];
                acc = __builtin_amdgcn_mfma_f32_16x16x32_bf16(aq[hf], bk, acc, 0, 0, 0);
            }
            s[sub] = acc;
        }
        __builtin_amdgcn_s_setprio(0);
        // ---- mask + scale ----
        #pragma unroll
        for (int sub = 0; sub < 4; ++sub) {
            int dk = dock[cur][sub * 16 + c];
            #pragma unroll
            for (int j = 0; j < 4; ++j)
                s[sub][j] = (dq[j] == dk) ? s[sub][j] * 0.125f : -1e30f;
        }
        // ---- tile row-max ----
        float mx[4];
        #pragma unroll
        for (int j = 0; j < 4; ++j)
            mx[j] = fmaxf(fmaxf(s[0][j], s[1][j]), fmaxf(s[2][j], s[3][j]));
        #pragma unroll
        for (int off = 1; off < 16; off <<= 1)
            #pragma unroll
            for (int j = 0; j < 4; ++j) mx[j] = fmaxf(mx[j], __shfl_xor(mx[j], off));
        // ---- online softmax update ----
        float mn[4], sc[4], rs[4];
        #pragma unroll
        for (int j = 0; j < 4; ++j) {
            mn[j] = fmaxf(m_[j], mx[j]);
            sc[j] = __expf(m_[j] - mn[j]);
            m_[j] = mn[j];
            rs[j] = 0.0f;
        }
        #pragma unroll
        for (int sub = 0; sub < 4; ++sub)
            #pragma unroll
            for (int j = 0; j < 4; ++j) {
                float p = __expf(s[sub][j] - mn[j]);
                rs[j] += p;
                Ps[wv][g * 4 + j][sub * 16 + c] = f2bf(p);
            }
        #pragma unroll
        for (int off = 1; off < 16; off <<= 1)
            #pragma unroll
            for (int j = 0; j < 4; ++j) rs[j] += __shfl_xor(rs[j], off);
        #pragma unroll
        for (int j = 0; j < 4; ++j) l_[j] = l_[j] * sc[j] + rs[j];
        #pragma unroll
        for (int nt = 0; nt < 4; ++nt)
            #pragma unroll
            for (int j = 0; j < 4; ++j) oacc[nt][j] *= sc[j];
        // ---- O += P V ----
        __builtin_amdgcn_s_setprio(1);
        #pragma unroll
        for (int hf = 0; hf < 2; ++hf) {
            bf16x8 af = *(const bf16x8*)&Ps[wv][c][hf * 32 + g * 8];
            #pragma unroll
            for (int nt = 0; nt < 4; ++nt) {
                bf16x8 bv = *(const bf16x8*)&Vt[cur][nt * 16 + c][hf * 32 + g * 8];
                oacc[nt] = __builtin_amdgcn_mfma_f32_16x16x32_bf16(af, bv, oacc[nt], 0, 0, 0);
            }
        }
        __builtin_amdgcn_s_setprio(0);

        if (more) writeV(cur ^ 1);   // V regs landed during compute
        __syncthreads();
    }

    #pragma unroll
    for (int j = 0; j < 4; ++j) {
        int row = mt * 16 + g * 4 + j;
        if (row < MM) {
            float invl = 1.0f / l_[j];
            #pragma unroll
            for (int nt = 0; nt < 4; ++nt)
                o[(size_t)(b * SS + rowq0 + row) * DD + h * 64 + nt * 16 + c] =
                    f2bf(oacc[nt][j] * invl);
        }
    }
}

// ---------------- extract router slots ----------------
__global__ void extract_k(const float* __restrict__ h, float* __restrict__ out) {
    int idx = blockIdx.x * blockDim.x + threadIdx.x;  // NB*LB*DD
    int d = idx % DD;
    int l = (idx / DD) % LB;
    int b = idx / (DD * LB);
    out[idx] = h[((size_t)(b * SS + l * MM + BLKN)) * DD + d];
}

extern "C" void kernel_launch(void* const* d_in, const int* in_sizes, int n_in,
                              void* d_out, int out_size, void* d_ws, size_t ws_size,
                              hipStream_t stream) {
    const float* x           = (const float*)d_in[0];
    const int*   doc         = (const int*)d_in[1];
    const float* rt          = (const float*)d_in[2];
    const float* attn_w      = (const float*)d_in[3];
    const float* attn_o_w    = (const float*)d_in[4];
    const float* ffn_up_w    = (const float*)d_in[5];
    const float* ffn_down_w  = (const float*)d_in[6];
    const float* attn_norm_w = (const float*)d_in[7];
    const float* ffn_norm_w  = (const float*)d_in[8];
    float* out = (float*)d_out;

    float* h = (float*)d_ws;                                      // ROWS*512 f32
    unsigned short* qkvb = (unsigned short*)(h + (size_t)ROWS * 512);  // ROWS*1536 bf16
    unsigned short* wt   = qkvb + (size_t)ROWS * 1536;            // 2*WT_LS bf16
    unsigned short* hnb  = wt + (size_t)2 * WT_LS;                // ROWS*512 bf16
    unsigned short* ob   = hnb + (size_t)ROWS * 512;              // ROWS*512 bf16
    unsigned short* gb   = ob + (size_t)ROWS * 512;               // ROWS*1024 bf16

    wtrans_all_k<<<1280, 256, 0, stream>>>(attn_w, attn_o_w, ffn_up_w, ffn_down_w, wt);

    for (int i = 0; i < 2; ++i) {
        unsigned short* wl = wt + (size_t)i * WT_LS;
        const float* anw = attn_norm_w + (size_t)i * 512;
        const float* fnw = ffn_norm_w  + (size_t)i * 512;

        if (i == 0)
            rms4_k<1><<<ROWS / 4, 256, 0, stream>>>(h, x, rt, anw, h, hnb);
        else
            rms4_k<0><<<ROWS / 4, 256, 0, stream>>>(h, x, rt, anw, h, hnb);
        gemm_bf16_k<0, 1, 1, 0><<<dim3(12, 65), 256, 0, stream>>>(hnb, wl, qkvb, 512, 1536);
        attn_mfma_k<<<512, 320, 0, stream>>>(qkvb, doc, ob);
        gemm_bf16_k<1, 0, 0, 0><<<dim3(4, 65), 256, 0, stream>>>(ob, wl + 786432, h, 512, 512);
        rms4_k<0><<<ROWS / 4, 256, 0, stream>>>(h, x, rt, fnw, h, hnb);
        gemm_bf16_k<0, 0, 0, 1><<<dim3(16, 65), 256, 0, stream>>>(hnb, wl + 1048576, gb, 512, 2048);
        gemm_bf16_k<1, 0, 0, 0><<<dim3(4, 65), 256, 0, stream>>>(gb, wl + 2097152, h, 1024, 512);
    }

    extract_k<<<(NB * LB * DD) / 256, 256, 0, stream>>>(h, out);
}